// Round 1
// baseline (473.554 us; speedup 1.0000x reference)
//
#include <hip/hip_runtime.h>

#define NB 4
#define NP 16384
#define DD 512
#define HH 256
#define CC 2
#define KSEL 11468
#define TOTP (NB*NP)

// d_out offsets (floats)
#define OFF_COMB (NB*KSEL*DD)            // 23486464
#define OFF_IDX  (OFF_COMB + NB*NP)      // 23552000
#define OFF_LOSS (OFF_IDX + NB*KSEL)     // 23597872

// ws offsets (floats)
#define WS_ALOGIT 0
#define WS_ATTN   (NB*CC*NP)             // 131072
#define WS_SELIDX (2*NB*CC*NP)           // 262144 (ints live here)
#define WS_CE     (WS_SELIDX + NB*KSEL)  // 308016

// ---------------------------------------------------------------------------
// Fused GEMM: a_logits[b,c,n] = Wbr[c] . relu(f[n] @ Wa + ba) + bbr[c]
// Block tile: 64 patches x 256 H (full H -> no cross-block reduction).
// Thread grid 16(tx: h) x 16(ty: patch); micro-tile 4 patches x 16 h.
// ---------------------------------------------------------------------------
__global__ __launch_bounds__(256) void gemm_attn_kernel(
    const float* __restrict__ feat, const float* __restrict__ Wa,
    const float* __restrict__ ba, const float* __restrict__ Wbr,
    const float* __restrict__ bbr, float* __restrict__ a_logits)
{
  __shared__ float wa_lds[8*HH];     // [kd][h]
  __shared__ float f_lds[8*68];      // [kd][patch], stride 68 (16B-aligned, skewed)
  const int tid = threadIdx.x;
  const int tx = tid & 15, ty = tid >> 4;
  const int p0 = blockIdx.x * 64;

  float acc[4][16];
  #pragma unroll
  for (int i=0;i<4;++i)
    #pragma unroll
    for (int j=0;j<16;++j) acc[i][j]=0.f;

  for (int k0=0; k0<DD; k0+=8){
    __syncthreads();
    // Wa tile: 8 rows x 256 cols = 512 float4, coalesced
    #pragma unroll
    for (int j=0;j<2;++j){
      int idx = j*256 + tid;
      int kd = idx >> 6, c4 = idx & 63;
      const float4 v = *reinterpret_cast<const float4*>(Wa + (size_t)(k0+kd)*HH + c4*4);
      *reinterpret_cast<float4*>(&wa_lds[kd*HH + c4*4]) = v;
    }
    // f tile: 64 patches x 8 k, stored transposed [kd][patch]
    if (tid < 128){
      int patch = tid >> 1, dch = tid & 1;
      const float4 v = *reinterpret_cast<const float4*>(feat + (size_t)(p0+patch)*DD + k0 + dch*4);
      f_lds[(dch*4+0)*68 + patch] = v.x;
      f_lds[(dch*4+1)*68 + patch] = v.y;
      f_lds[(dch*4+2)*68 + patch] = v.z;
      f_lds[(dch*4+3)*68 + patch] = v.w;
    }
    __syncthreads();
    #pragma unroll
    for (int kd=0; kd<8; ++kd){
      float4 a = *reinterpret_cast<const float4*>(&f_lds[kd*68 + ty*4]);
      float fa[4] = {a.x,a.y,a.z,a.w};
      #pragma unroll
      for (int g=0; g<4; ++g){
        float4 w = *reinterpret_cast<const float4*>(&wa_lds[kd*HH + g*64 + tx*4]);
        float fw[4] = {w.x,w.y,w.z,w.w};
        #pragma unroll
        for (int i=0;i<4;++i)
          #pragma unroll
          for (int u=0;u<4;++u)
            acc[i][g*4+u] += fa[i]*fw[u];
      }
    }
  }
  // epilogue: relu + project with Wbr, reduce across the 16 tx lanes
  const int b = p0 / NP;
  #pragma unroll
  for (int i=0;i<4;++i){
    float s0=0.f, s1=0.f;
    #pragma unroll
    for (int g=0; g<4; ++g)
      #pragma unroll
      for (int u=0; u<4; ++u){
        int h = g*64 + tx*4 + u;
        float hv = acc[i][g*4+u] + ba[h];
        hv = fmaxf(hv, 0.f);
        s0 += hv * Wbr[h];
        s1 += hv * Wbr[HH + h];
      }
    #pragma unroll
    for (int off=1; off<16; off<<=1){
      s0 += __shfl_xor(s0, off);
      s1 += __shfl_xor(s1, off);
    }
    if (tx == 0){
      int n = p0 + ty*4 + i;
      int nl = n & (NP-1);
      a_logits[((size_t)b*CC + 0)*NP + nl] = s0 + bbr[0];
      a_logits[((size_t)b*CC + 1)*NP + nl] = s1 + bbr[1];
    }
  }
}

// ---------------------------------------------------------------------------
// Softmax per (b,c) row; double accumulation for the denominator.
// ---------------------------------------------------------------------------
__global__ __launch_bounds__(1024) void softmax_kernel(
    const float* __restrict__ a_logits, float* __restrict__ attn)
{
  __shared__ float  s_redf[16];
  __shared__ double s_redd[16];
  __shared__ float  s_max;
  __shared__ double s_sum;
  const int tid = threadIdx.x;
  const int lane = tid & 63, wid = tid >> 6;
  const float* a = a_logits + (size_t)blockIdx.x*NP;
  float m = -1e30f;
  for (int n=tid; n<NP; n+=1024) m = fmaxf(m, a[n]);
  #pragma unroll
  for (int off=1; off<64; off<<=1) m = fmaxf(m, __shfl_xor(m, off));
  if (lane==0) s_redf[wid]=m;
  __syncthreads();
  if (tid==0){ float mm=s_redf[0]; for(int w=1;w<16;++w) mm=fmaxf(mm,s_redf[w]); s_max=mm; }
  __syncthreads();
  m = s_max;
  double ls = 0.0;
  for (int n=tid;n<NP;n+=1024) ls += exp((double)(a[n]-m));
  #pragma unroll
  for (int off=1; off<64; off<<=1) ls += __shfl_xor(ls, off);
  if (lane==0) s_redd[wid]=ls;
  __syncthreads();
  if (tid==0){ double t=0; for(int w=0;w<16;++w) t+=s_redd[w]; s_sum=t; }
  __syncthreads();
  const double inv = 1.0 / s_sum;
  float* o = attn + (size_t)blockIdx.x*NP;
  for (int n=tid;n<NP;n+=1024) o[n] = (float)(exp((double)(a[n]-m)) * inv);
}

__global__ __launch_bounds__(256) void combined_kernel(
    const float* __restrict__ attn, float* __restrict__ comb)
{
  int i = blockIdx.x*256 + threadIdx.x;
  int b = i >> 14, n = i & (NP-1);
  float v0 = attn[((size_t)b*CC + 0)*NP + n];
  float v1 = attn[((size_t)b*CC + 1)*NP + n];
  comb[i] = 0.5f*(v0+v1);
}

// ---------------------------------------------------------------------------
// Per-batch top-k selection: radix-select threshold on float bits (all values
// positive), then stable ordered compaction -> ascending sel_idx directly.
// LDS layout transposed+skewed: element n=(t*16+e) at s_bits[e*1028+t].
// ---------------------------------------------------------------------------
#define SKW 1028
__global__ __launch_bounds__(1024) void select_kernel(
    const float* __restrict__ comb, float* __restrict__ outIdxF,
    int* __restrict__ selIdx)
{
  __shared__ unsigned s_bits[16*SKW];
  __shared__ unsigned s_red[16];
  __shared__ unsigned s_scan[1024];
  __shared__ unsigned s_bcast;
  const int tid = threadIdx.x;
  const int b = blockIdx.x;
  const int lane = tid & 63, wid = tid >> 6;
  const float* row = comb + (size_t)b*NP;
  for (int j=0;j<16;++j){
    int n = tid + j*1024;
    s_bits[(n & 15)*SKW + (n >> 4)] = __float_as_uint(row[n]);
  }
  __syncthreads();
  // radix select k-th largest bit pattern
  unsigned cur = 0;
  for (int bit=31; bit>=0; --bit){
    unsigned trial = cur | (1u<<bit);
    int c = 0;
    #pragma unroll
    for (int j=0;j<16;++j) c += (s_bits[j*SKW + tid] >= trial) ? 1 : 0;
    #pragma unroll
    for (int off=1; off<64; off<<=1) c += __shfl_xor(c, off);
    if (lane==0) s_red[wid] = (unsigned)c;
    __syncthreads();
    if (tid==0){ unsigned t=0; for(int w=0;w<16;++w) t+=s_red[w]; s_bcast=t; }
    __syncthreads();
    if (s_bcast >= KSEL) cur = trial;
    __syncthreads();
  }
  const unsigned T = cur;
  // count strictly greater
  {
    int c = 0;
    #pragma unroll
    for (int j=0;j<16;++j) c += (s_bits[j*SKW + tid] > T) ? 1 : 0;
    #pragma unroll
    for (int off=1; off<64; off<<=1) c += __shfl_xor(c, off);
    if (lane==0) s_red[wid] = (unsigned)c;
    __syncthreads();
    if (tid==0){ unsigned t=0; for(int w=0;w<16;++w) t+=s_red[w]; s_bcast=t; }
    __syncthreads();
  }
  const int extra = KSEL - (int)s_bcast;
  __syncthreads();
  // prefix of equality counts (for stable tie-break by index)
  int eqc=0;
  #pragma unroll
  for (int e=0;e<16;++e) eqc += (s_bits[e*SKW + tid]==T) ? 1 : 0;
  s_scan[tid]=(unsigned)eqc;
  __syncthreads();
  for (int off=1; off<1024; off<<=1){
    unsigned v = (tid>=off)? s_scan[tid-off] : 0u;
    __syncthreads();
    s_scan[tid]+=v;
    __syncthreads();
  }
  const int eqBase = (int)s_scan[tid] - eqc;
  __syncthreads();
  // selected count per thread-chunk
  int eq=eqBase, sc=0;
  #pragma unroll
  for (int e=0;e<16;++e){
    unsigned v = s_bits[e*SKW + tid];
    if (v==T){ if (eq<extra) sc++; eq++; }
    else if (v>T) sc++;
  }
  s_scan[tid]=(unsigned)sc;
  __syncthreads();
  for (int off=1; off<1024; off<<=1){
    unsigned v = (tid>=off)? s_scan[tid-off] : 0u;
    __syncthreads();
    s_scan[tid]+=v;
    __syncthreads();
  }
  int pos = (int)s_scan[tid] - sc;
  eq=eqBase;
  #pragma unroll
  for (int e=0;e<16;++e){
    unsigned v = s_bits[e*SKW + tid];
    int f=0;
    if (v==T){ if (eq<extra) f=1; eq++; }
    else if (v>T) f=1;
    if (f){
      int n = tid*16 + e;
      outIdxF[(size_t)b*KSEL + pos] = (float)n;
      selIdx[(size_t)b*KSEL + pos] = n;
      pos++;
    }
  }
}

// ---------------------------------------------------------------------------
// Gather selected feature rows (2 rows per 256-thread block, float4).
// ---------------------------------------------------------------------------
__global__ __launch_bounds__(256) void gather_kernel(
    const float* __restrict__ feat, const int* __restrict__ selIdx,
    float* __restrict__ outSel)
{
  const int tid = threadIdx.x;
  const int row = blockIdx.x*2 + (tid>>7);
  const int c4 = tid & 127;
  const int b = row / KSEL;
  const int idx = selIdx[row];
  const float4 v = *reinterpret_cast<const float4*>(feat + ((size_t)b*NP + idx)*DD + c4*4);
  *reinterpret_cast<float4*>(outSel + (size_t)row*DD + c4*4) = v;
}

// ---------------------------------------------------------------------------
// Per-(b,c): top-8 / bottom-8 of attn (lax.top_k tie semantics), instance MLP,
// CE loss partial (fixed order, no atomics).
// ---------------------------------------------------------------------------
__global__ __launch_bounds__(256) void inst_kernel(
    const float* __restrict__ feat, const float* __restrict__ attn,
    const float* __restrict__ W1, const float* __restrict__ b1,
    const float* __restrict__ W2, const float* __restrict__ b2,
    float* __restrict__ ce_ws)
{
  __shared__ float s_vals[NP];       // 64 KB
  __shared__ float f_l[DD];
  __shared__ unsigned long long s_k[4];
  __shared__ float s_r0[4], s_r1[4];
  __shared__ int s_idx16[16];

  const int tid = threadIdx.x;
  const int bid = blockIdx.x;
  const int b = bid >> 1, c = bid & 1;
  const int lane = tid & 63, wid = tid >> 6;
  const float* arow = attn + (size_t)bid*NP;
  for (int n=tid;n<NP;n+=256) s_vals[n]=arow[n];
  __syncthreads();
  // top 8 (max value, tie -> smallest index)
  for (int pick=0; pick<8; ++pick){
    unsigned long long bk = 0ull;
    for (int n=tid;n<NP;n+=256){
      unsigned vb = __float_as_uint(s_vals[n]);
      unsigned long long key = ((unsigned long long)vb<<32) | (unsigned)(NP-1-n);
      bk = key>bk ? key : bk;
    }
    #pragma unroll
    for (int off=1; off<64; off<<=1){
      unsigned long long o = __shfl_xor(bk, off);
      bk = o>bk ? o : bk;
    }
    if (lane==0) s_k[wid]=bk;
    __syncthreads();
    if (tid==0){
      unsigned long long m=s_k[0];
      for (int w=1;w<4;++w) m = s_k[w]>m ? s_k[w] : m;
      int idx = NP-1-(int)(m & 0xFFFFFFFFull);
      s_idx16[pick]=idx;
      s_vals[idx]=0.f;   // attn strictly > 0, so bits 0 excludes
    }
    __syncthreads();
  }
  // restore the 8 excluded entries
  if (tid<8){ int ix=s_idx16[tid]; s_vals[ix]=arow[ix]; }
  __syncthreads();
  // bottom 8 (min value, tie -> smallest index)
  for (int pick=8; pick<16; ++pick){
    unsigned long long bk = ~0ull;
    for (int n=tid;n<NP;n+=256){
      unsigned vb = __float_as_uint(s_vals[n]);
      unsigned long long key = ((unsigned long long)vb<<32) | (unsigned)n;
      bk = key<bk ? key : bk;
    }
    #pragma unroll
    for (int off=1; off<64; off<<=1){
      unsigned long long o = __shfl_xor(bk, off);
      bk = o<bk ? o : bk;
    }
    if (lane==0) s_k[wid]=bk;
    __syncthreads();
    if (tid==0){
      unsigned long long m=s_k[0];
      for (int w=1;w<4;++w) m = s_k[w]<m ? s_k[w] : m;
      int idx = (int)(m & 0xFFFFFFFFull);
      s_idx16[pick]=idx;
      s_vals[idx]=__uint_as_float(0x7F800000u);  // +inf excludes from min
    }
    __syncthreads();
  }
  // instance MLP + CE
  float lsum = 0.f;
  const float* w1c = W1 + (size_t)c*DD*HH;
  const float b1v = b1[c*HH + tid];
  const float w20 = W2[(c*HH + tid)*2 + 0];
  const float w21 = W2[(c*HH + tid)*2 + 1];
  for (int r=0; r<16; ++r){
    __syncthreads();
    if (tid<128){
      int gi = s_idx16[r];
      const float4 v = *reinterpret_cast<const float4*>(feat + ((size_t)b*NP + gi)*DD + tid*4);
      *reinterpret_cast<float4*>(&f_l[tid*4]) = v;
    }
    __syncthreads();
    float a0=0.f,a1=0.f,a2=0.f,a3=0.f;
    #pragma unroll 4
    for (int d=0; d<DD; d+=4){
      a0 += f_l[d+0]*w1c[(size_t)(d+0)*HH + tid];
      a1 += f_l[d+1]*w1c[(size_t)(d+1)*HH + tid];
      a2 += f_l[d+2]*w1c[(size_t)(d+2)*HH + tid];
      a3 += f_l[d+3]*w1c[(size_t)(d+3)*HH + tid];
    }
    float h1 = fmaxf((a0+a1)+(a2+a3) + b1v, 0.f);
    float p0 = h1*w20, p1 = h1*w21;
    #pragma unroll
    for (int off=1; off<64; off<<=1){ p0+=__shfl_xor(p0,off); p1+=__shfl_xor(p1,off); }
    if (lane==0){ s_r0[wid]=p0; s_r1[wid]=p1; }
    __syncthreads();
    if (tid==0){
      float l0=b2[c*2+0], l1=b2[c*2+1];
      for (int w=0;w<4;++w){ l0+=s_r0[w]; l1+=s_r1[w]; }
      float mm = fmaxf(l0,l1);
      float lse = mm + logf(expf(l0-mm)+expf(l1-mm));
      float chosen = (r<8) ? l1 : l0;   // labels: first 8 -> 1, last 8 -> 0
      lsum += (lse - chosen);
    }
  }
  if (tid==0) ce_ws[bid] = lsum;
}

__global__ void loss_kernel(const float* __restrict__ ce_ws, float* __restrict__ out_loss){
  if (threadIdx.x==0 && blockIdx.x==0){
    float s=0.f;
    for (int i=0;i<NB*CC;++i) s += ce_ws[i];
    out_loss[0] = s / (float)(NB*CC*16);
  }
}

extern "C" void kernel_launch(void* const* d_in, const int* in_sizes, int n_in,
                              void* d_out, int out_size, void* d_ws, size_t ws_size,
                              hipStream_t stream) {
  const float* feat = (const float*)d_in[0];
  const float* Wa   = (const float*)d_in[1];
  const float* ba   = (const float*)d_in[2];
  const float* Wbr  = (const float*)d_in[3];
  const float* bbr  = (const float*)d_in[4];
  const float* W1   = (const float*)d_in[5];
  const float* b1   = (const float*)d_in[6];
  const float* W2   = (const float*)d_in[7];
  const float* b2   = (const float*)d_in[8];
  float* out = (float*)d_out;
  float* ws  = (float*)d_ws;

  float* a_logits = ws + WS_ALOGIT;
  float* attn     = ws + WS_ATTN;
  int*   selIdx   = (int*)(ws + WS_SELIDX);
  float* ce_ws    = ws + WS_CE;

  hipLaunchKernelGGL(gemm_attn_kernel, dim3(TOTP/64), dim3(256), 0, stream,
                     feat, Wa, ba, Wbr, bbr, a_logits);
  hipLaunchKernelGGL(softmax_kernel, dim3(NB*CC), dim3(1024), 0, stream,
                     a_logits, attn);
  hipLaunchKernelGGL(combined_kernel, dim3(TOTP/256), dim3(256), 0, stream,
                     attn, out + OFF_COMB);
  hipLaunchKernelGGL(select_kernel, dim3(NB), dim3(1024), 0, stream,
                     out + OFF_COMB, out + OFF_IDX, selIdx);
  hipLaunchKernelGGL(gather_kernel, dim3(NB*KSEL/2), dim3(256), 0, stream,
                     feat, selIdx, out);
  hipLaunchKernelGGL(inst_kernel, dim3(NB*CC), dim3(256), 0, stream,
                     feat, attn, W1, b1, W2, b2, ce_ws);
  hipLaunchKernelGGL(loss_kernel, dim3(1), dim3(64), 0, stream,
                     ce_ws, out + OFF_LOSS);
}

// Round 2
// 356.418 us; speedup vs baseline: 1.3286x; 1.3286x over previous
//
#include <hip/hip_runtime.h>

#define NB 4
#define NP 16384
#define DD 512
#define HH 256
#define CC 2
#define KSEL 11468
#define TOTP (NB*NP)
#define BCAP 4096

// d_out offsets (floats)
#define OFF_COMB (NB*KSEL*DD)            // 23486464
#define OFF_IDX  (OFF_COMB + NB*NP)      // 23552000
#define OFF_LOSS (OFF_IDX + NB*KSEL)     // 23597872

// ws offsets (floats)
#define WS_ALOGIT 0
#define WS_ATTN   (NB*CC*NP)                 // 131072
#define WS_SELIDX (2*NB*CC*NP)               // 262144 (ints)
#define WS_MZ     (WS_SELIDX + NB*KSEL)      // 308016 (16 floats)
#define WS_BCNT   (WS_MZ + 16)               // ints (4)
#define WS_BLIST  (WS_BCNT + 4)              // ints (4*BCAP)
#define WS_TOP16  (WS_BLIST + NB*BCAP)       // ints (8*16)
#define WS_CE     (WS_TOP16 + 128)           // floats (128)

typedef __attribute__((ext_vector_type(8))) short short8x;
typedef __attribute__((ext_vector_type(4))) float f32x4;

__device__ __forceinline__ unsigned short f2bf(float x){
  unsigned u = __float_as_uint(x);
  unsigned r = (u + 0x7FFFu + ((u >> 16) & 1u)) >> 16;
  return (unsigned short)r;
}

// ---------------------------------------------------------------------------
// Wa (512x256 f32) -> Wa_t (256x512 bf16), transposed, stored at d_out head.
// ---------------------------------------------------------------------------
__global__ __launch_bounds__(256) void waconv_kernel(
    const float* __restrict__ Wa, unsigned short* __restrict__ WaT)
{
  __shared__ float tile[32][33];
  const int tx = threadIdx.x, ty = threadIdx.y;   // 32 x 8
  const int k0 = blockIdx.x * 32, n0 = blockIdx.y * 32;
  #pragma unroll
  for (int i=0;i<4;++i)
    tile[ty+8*i][tx] = Wa[(size_t)(k0+ty+8*i)*HH + n0 + tx];
  __syncthreads();
  #pragma unroll
  for (int i=0;i<4;++i)
    WaT[(size_t)(n0+ty+8*i)*DD + k0 + tx] = f2bf(tile[tx][ty+8*i]);
}

// ---------------------------------------------------------------------------
// MFMA GEMM: a_logits[b,c,n] = Wbr[c].relu(f[n]@Wa+ba) + bbr[c], bf16 inputs.
// BM=128, BN=256(full H), BK=64; 8 waves (2M x 4N), wave tile 64x64.
// ---------------------------------------------------------------------------
__global__ __launch_bounds__(512) void gemm_mfma_kernel(
    const float* __restrict__ feat, const unsigned short* __restrict__ WaT,
    const float* __restrict__ ba, const float* __restrict__ Wbr,
    const float* __restrict__ bbr, float* __restrict__ aL)
{
  __shared__ __attribute__((aligned(16))) unsigned char smem[65536];
  __shared__ float sBA[HH], sW0[HH], sW1[HH];
  unsigned char* sA = smem;                 // 128*64 bf16 = 16 KB (swizzled)
  unsigned char* sB = smem + 16384;         // 256*64 bf16 = 32 KB (swizzled)

  const int tid  = threadIdx.x;
  const int lane = tid & 63;
  const int wid  = tid >> 6;
  const int wm = wid >> 2, wn = wid & 3;
  const int fr = lane & 15, fq = lane >> 4;
  const int p0 = blockIdx.x * 128;
  const float bb0 = bbr[0], bb1 = bbr[1];

  if (tid < HH){ sBA[tid] = ba[tid]; sW0[tid] = Wbr[tid]; sW1[tid] = Wbr[HH+tid]; }

  f32x4 acc[4][4];
  #pragma unroll
  for (int i=0;i<4;++i)
    #pragma unroll
    for (int j=0;j<4;++j)
      acc[i][j] = (f32x4){0.f,0.f,0.f,0.f};

  const int am = tid >> 2, akq = (tid & 3) * 16;     // A staging: row, k-offset
  const int bn = tid >> 1, bhf = tid & 1;            // B staging

  for (int k0 = 0; k0 < DD; k0 += 64){
    __syncthreads();
    // ---- stage A: 128x64 fp32 -> bf16, swizzled K-major
    {
      const float4* src = reinterpret_cast<const float4*>(
          feat + (size_t)(p0 + am)*DD + k0 + akq);
      float4 v0 = src[0], v1 = src[1], v2 = src[2], v3 = src[3];
      unsigned short u[16];
      u[0]=f2bf(v0.x); u[1]=f2bf(v0.y); u[2]=f2bf(v0.z); u[3]=f2bf(v0.w);
      u[4]=f2bf(v1.x); u[5]=f2bf(v1.y); u[6]=f2bf(v1.z); u[7]=f2bf(v1.w);
      u[8]=f2bf(v2.x); u[9]=f2bf(v2.y); u[10]=f2bf(v2.z); u[11]=f2bf(v2.w);
      u[12]=f2bf(v3.x); u[13]=f2bf(v3.y); u[14]=f2bf(v3.z); u[15]=f2bf(v3.w);
      uint4 w0, w1;
      w0.x = (unsigned)u[0] | ((unsigned)u[1]<<16);
      w0.y = (unsigned)u[2] | ((unsigned)u[3]<<16);
      w0.z = (unsigned)u[4] | ((unsigned)u[5]<<16);
      w0.w = (unsigned)u[6] | ((unsigned)u[7]<<16);
      w1.x = (unsigned)u[8] | ((unsigned)u[9]<<16);
      w1.y = (unsigned)u[10] | ((unsigned)u[11]<<16);
      w1.z = (unsigned)u[12] | ((unsigned)u[13]<<16);
      w1.w = (unsigned)u[14] | ((unsigned)u[15]<<16);
      const int swz = (am & 7) << 4;
      *reinterpret_cast<uint4*>(sA + (((am*128) + akq*2) ^ swz)) = w0;
      *reinterpret_cast<uint4*>(sA + (((am*128) + akq*2 + 16) ^ swz)) = w1;
    }
    // ---- stage B: 256x64 bf16 from WaT, swizzled K-major
    {
      const uint4* src = reinterpret_cast<const uint4*>(
          WaT + (size_t)bn*DD + k0 + bhf*32);
      uint4 q0 = src[0], q1 = src[1], q2 = src[2], q3 = src[3];
      const int swz = (bn & 7) << 4;
      const int base = bn*128 + bhf*64;
      *reinterpret_cast<uint4*>(sB + ((base     ) ^ swz)) = q0;
      *reinterpret_cast<uint4*>(sB + ((base + 16) ^ swz)) = q1;
      *reinterpret_cast<uint4*>(sB + ((base + 32) ^ swz)) = q2;
      *reinterpret_cast<uint4*>(sB + ((base + 48) ^ swz)) = q3;
    }
    __syncthreads();
    // ---- MFMA
    #pragma unroll
    for (int kf = 0; kf < 2; ++kf){
      short8x af[4], bf[4];
      #pragma unroll
      for (int mf = 0; mf < 4; ++mf){
        int m_loc = wm*64 + mf*16 + fr;
        int off = ((m_loc*128 + kf*64 + fq*16) ^ ((m_loc & 7) << 4));
        af[mf] = *reinterpret_cast<const short8x*>(sA + off);
      }
      #pragma unroll
      for (int nf = 0; nf < 4; ++nf){
        int n_loc = wn*64 + nf*16 + fr;
        int off = ((n_loc*128 + kf*64 + fq*16) ^ ((n_loc & 7) << 4));
        bf[nf] = *reinterpret_cast<const short8x*>(sB + off);
      }
      #pragma unroll
      for (int mf = 0; mf < 4; ++mf)
        #pragma unroll
        for (int nf = 0; nf < 4; ++nf)
          acc[mf][nf] = __builtin_amdgcn_mfma_f32_16x16x32_bf16(
              af[mf], bf[nf], acc[mf][nf], 0, 0, 0);
    }
  }
  __syncthreads();

  // ---- epilogue: relu + Wbr projection via LDS h-tile, M in halves of 64
  float* hS = reinterpret_cast<float*>(smem);
  #pragma unroll
  for (int mh = 0; mh < 2; ++mh){
    if (wm == mh){
      #pragma unroll
      for (int mf = 0; mf < 4; ++mf)
        #pragma unroll
        for (int nf = 0; nf < 4; ++nf)
          #pragma unroll
          for (int r = 0; r < 4; ++r){
            int row = mf*16 + fq*4 + r;
            int col = wn*64 + nf*16 + fr;
            hS[row*256 + col] = acc[mf][nf][r];
          }
    }
    __syncthreads();
    {
      const int row = tid >> 3, cg = tid & 7;
      float s0 = 0.f, s1 = 0.f;
      #pragma unroll
      for (int j = 0; j < 8; ++j){
        int col = cg*4 + j*32;
        float4 hv = *reinterpret_cast<const float4*>(&hS[row*256 + col]);
        float xs[4] = {hv.x, hv.y, hv.z, hv.w};
        #pragma unroll
        for (int u = 0; u < 4; ++u){
          int ccol = col + u;
          float x = fmaxf(xs[u] + sBA[ccol], 0.f);
          s0 += x * sW0[ccol];
          s1 += x * sW1[ccol];
        }
      }
      s0 += __shfl_xor(s0,1); s1 += __shfl_xor(s1,1);
      s0 += __shfl_xor(s0,2); s1 += __shfl_xor(s1,2);
      s0 += __shfl_xor(s0,4); s1 += __shfl_xor(s1,4);
      if (cg == 0){
        int p = p0 + mh*64 + row;
        int b = p >> 14, nl = p & (NP-1);
        aL[((size_t)b*CC + 0)*NP + nl] = s0 + bb0;
        aL[((size_t)b*CC + 1)*NP + nl] = s1 + bb1;
      }
    }
    __syncthreads();
  }
}

// ---------------------------------------------------------------------------
// Softmax both classes + combined, store m and 1/Z per (b,c) for refinement.
// ---------------------------------------------------------------------------
__global__ __launch_bounds__(1024) void softmax2_kernel(
    const float* __restrict__ aL, float* __restrict__ attn,
    float* __restrict__ comb, float* __restrict__ mz)
{
  __shared__ float  s_redf[16];
  __shared__ double s_redd[16];
  __shared__ float  s_m[2];
  __shared__ float  s_iz[2];
  const int tid = threadIdx.x;
  const int lane = tid & 63, wid = tid >> 6;
  const int b = blockIdx.x;

  #pragma unroll
  for (int c = 0; c < 2; ++c){
    const float* a = aL + ((size_t)b*CC + c)*NP;
    float m = -1e30f;
    for (int n = tid; n < NP; n += 1024) m = fmaxf(m, a[n]);
    #pragma unroll
    for (int off=1; off<64; off<<=1) m = fmaxf(m, __shfl_xor(m, off));
    if (lane==0) s_redf[wid] = m;
    __syncthreads();
    if (tid==0){ float mm=s_redf[0]; for(int w=1;w<16;++w) mm=fmaxf(mm,s_redf[w]); s_m[c]=mm; }
    __syncthreads();
    m = s_m[c];
    double ls = 0.0;
    for (int n = tid; n < NP; n += 1024) ls += (double)expf(a[n]-m);
    #pragma unroll
    for (int off=1; off<64; off<<=1) ls += __shfl_xor(ls, off);
    if (lane==0) s_redd[wid] = ls;
    __syncthreads();
    if (tid==0){ double t=0; for(int w=0;w<16;++w) t+=s_redd[w]; s_iz[c]=(float)(1.0/t); }
    __syncthreads();
  }
  const float m0 = s_m[0], iz0 = s_iz[0], m1 = s_m[1], iz1 = s_iz[1];
  const float* a0 = aL + ((size_t)b*CC + 0)*NP;
  const float* a1 = aL + ((size_t)b*CC + 1)*NP;
  float* o0 = attn + ((size_t)b*CC + 0)*NP;
  float* o1 = attn + ((size_t)b*CC + 1)*NP;
  float* oc = comb + (size_t)b*NP;
  for (int n = tid; n < NP; n += 1024){
    float e0 = expf(a0[n]-m0)*iz0;
    float e1 = expf(a1[n]-m1)*iz1;
    o0[n] = e0; o1[n] = e1; oc[n] = 0.5f*(e0+e1);
  }
  if (tid==0){ mz[b*4+0]=m0; mz[b*4+1]=iz0; mz[b*4+2]=m1; mz[b*4+3]=iz1; }
}

// ---------------------------------------------------------------------------
// Approximate threshold (top 20 bits) + band list for refinement.
// ---------------------------------------------------------------------------
#define SKW 1028
__global__ __launch_bounds__(1024) void selT_kernel(
    const float* __restrict__ comb, int* __restrict__ bcnt,
    int* __restrict__ blist)
{
  __shared__ unsigned s_bits[16*SKW];
  __shared__ unsigned s_red[16];
  __shared__ unsigned s_bcast;
  __shared__ int s_cnt;
  const int tid = threadIdx.x;
  const int b = blockIdx.x;
  const int lane = tid & 63, wid = tid >> 6;
  const float* row = comb + (size_t)b*NP;
  for (int j=0;j<16;++j){
    int n = tid + j*1024;
    s_bits[(n & 15)*SKW + (n >> 4)] = __float_as_uint(row[n]);
  }
  if (tid==0) s_cnt = 0;
  __syncthreads();
  unsigned cur = 0;
  for (int bit=31; bit>=12; --bit){
    unsigned trial = cur | (1u<<bit);
    int c = 0;
    #pragma unroll
    for (int j=0;j<16;++j) c += (s_bits[j*SKW + tid] >= trial) ? 1 : 0;
    #pragma unroll
    for (int off=1; off<64; off<<=1) c += __shfl_xor(c, off);
    if (lane==0) s_red[wid] = (unsigned)c;
    __syncthreads();
    if (tid==0){ unsigned t=0; for(int w=0;w<16;++w) t+=s_red[w]; s_bcast=t; }
    __syncthreads();
    if (s_bcast >= KSEL) cur = trial;
    __syncthreads();
  }
  const float Tv = __uint_as_float(cur);
  const float lo = Tv*0.989f, hi = Tv*1.0115f;
  #pragma unroll
  for (int e=0;e<16;++e){
    float v = __uint_as_float(s_bits[e*SKW + tid]);
    if (v >= lo && v <= hi){
      int s = atomicAdd(&s_cnt, 1);
      if (s < BCAP) blist[b*BCAP + s] = tid*16 + e;
    }
  }
  __syncthreads();
  if (tid==0) bcnt[b] = (s_cnt < BCAP) ? s_cnt : BCAP;
}

// ---------------------------------------------------------------------------
// Exact fp32 recompute of combined for band members.
// ---------------------------------------------------------------------------
__global__ __launch_bounds__(256) void recomp_kernel(
    const float* __restrict__ feat, const float* __restrict__ Wa,
    const float* __restrict__ ba, const float* __restrict__ Wbr,
    const float* __restrict__ bbr, const float* __restrict__ mz,
    const int* __restrict__ bcnt, const int* __restrict__ blist,
    float* __restrict__ comb)
{
  __shared__ float fS[DD];
  __shared__ float r0[4], r1[4];
  const int tid = threadIdx.x;
  const int b = blockIdx.x >> 6, s0i = blockIdx.x & 63;
  const int cnt = bcnt[b];
  const int lane = tid & 63, wid = tid >> 6;
  const float m0 = mz[b*4+0], iz0 = mz[b*4+1], m1 = mz[b*4+2], iz1 = mz[b*4+3];
  const float bb0 = bbr[0], bb1 = bbr[1];
  for (int s = s0i; s < cnt; s += 64){
    const int n = blist[b*BCAP + s];
    __syncthreads();
    if (tid < 128){
      float4 v = *reinterpret_cast<const float4*>(feat + ((size_t)b*NP + n)*DD + tid*4);
      *reinterpret_cast<float4*>(&fS[tid*4]) = v;
    }
    __syncthreads();
    float a0=0.f,a1=0.f,a2=0.f,a3=0.f;
    #pragma unroll 4
    for (int d=0; d<DD; d+=4){
      a0 += fS[d+0]*Wa[(size_t)(d+0)*HH + tid];
      a1 += fS[d+1]*Wa[(size_t)(d+1)*HH + tid];
      a2 += fS[d+2]*Wa[(size_t)(d+2)*HH + tid];
      a3 += fS[d+3]*Wa[(size_t)(d+3)*HH + tid];
    }
    float h = fmaxf((a0+a1)+(a2+a3) + ba[tid], 0.f);
    float p0 = h*Wbr[tid], p1 = h*Wbr[HH+tid];
    #pragma unroll
    for (int off=1; off<64; off<<=1){ p0+=__shfl_xor(p0,off); p1+=__shfl_xor(p1,off); }
    if (lane==0){ r0[wid]=p0; r1[wid]=p1; }
    __syncthreads();
    if (tid==0){
      float l0 = (r0[0]+r0[1])+(r0[2]+r0[3]) + bb0;
      float l1 = (r1[0]+r1[1])+(r1[2]+r1[3]) + bb1;
      comb[(size_t)b*NP + n] = 0.5f*(expf(l0-m0)*iz0 + expf(l1-m1)*iz1);
    }
  }
}

// ---------------------------------------------------------------------------
// Exact top-k selection on refined combined (round-1 proven kernel).
// ---------------------------------------------------------------------------
__global__ __launch_bounds__(1024) void select_kernel(
    const float* __restrict__ comb, float* __restrict__ outIdxF,
    int* __restrict__ selIdx)
{
  __shared__ unsigned s_bits[16*SKW];
  __shared__ unsigned s_red[16];
  __shared__ unsigned s_scan[1024];
  __shared__ unsigned s_bcast;
  const int tid = threadIdx.x;
  const int b = blockIdx.x;
  const int lane = tid & 63, wid = tid >> 6;
  const float* row = comb + (size_t)b*NP;
  for (int j=0;j<16;++j){
    int n = tid + j*1024;
    s_bits[(n & 15)*SKW + (n >> 4)] = __float_as_uint(row[n]);
  }
  __syncthreads();
  unsigned cur = 0;
  for (int bit=31; bit>=0; --bit){
    unsigned trial = cur | (1u<<bit);
    int c = 0;
    #pragma unroll
    for (int j=0;j<16;++j) c += (s_bits[j*SKW + tid] >= trial) ? 1 : 0;
    #pragma unroll
    for (int off=1; off<64; off<<=1) c += __shfl_xor(c, off);
    if (lane==0) s_red[wid] = (unsigned)c;
    __syncthreads();
    if (tid==0){ unsigned t=0; for(int w=0;w<16;++w) t+=s_red[w]; s_bcast=t; }
    __syncthreads();
    if (s_bcast >= KSEL) cur = trial;
    __syncthreads();
  }
  const unsigned T = cur;
  {
    int c = 0;
    #pragma unroll
    for (int j=0;j<16;++j) c += (s_bits[j*SKW + tid] > T) ? 1 : 0;
    #pragma unroll
    for (int off=1; off<64; off<<=1) c += __shfl_xor(c, off);
    if (lane==0) s_red[wid] = (unsigned)c;
    __syncthreads();
    if (tid==0){ unsigned t=0; for(int w=0;w<16;++w) t+=s_red[w]; s_bcast=t; }
    __syncthreads();
  }
  const int extra = KSEL - (int)s_bcast;
  __syncthreads();
  int eqc=0;
  #pragma unroll
  for (int e=0;e<16;++e) eqc += (s_bits[e*SKW + tid]==T) ? 1 : 0;
  s_scan[tid]=(unsigned)eqc;
  __syncthreads();
  for (int off=1; off<1024; off<<=1){
    unsigned v = (tid>=off)? s_scan[tid-off] : 0u;
    __syncthreads();
    s_scan[tid]+=v;
    __syncthreads();
  }
  const int eqBase = (int)s_scan[tid] - eqc;
  __syncthreads();
  int eq=eqBase, sc=0;
  #pragma unroll
  for (int e=0;e<16;++e){
    unsigned v = s_bits[e*SKW + tid];
    if (v==T){ if (eq<extra) sc++; eq++; }
    else if (v>T) sc++;
  }
  s_scan[tid]=(unsigned)sc;
  __syncthreads();
  for (int off=1; off<1024; off<<=1){
    unsigned v = (tid>=off)? s_scan[tid-off] : 0u;
    __syncthreads();
    s_scan[tid]+=v;
    __syncthreads();
  }
  int pos = (int)s_scan[tid] - sc;
  eq=eqBase;
  #pragma unroll
  for (int e=0;e<16;++e){
    unsigned v = s_bits[e*SKW + tid];
    int f=0;
    if (v==T){ if (eq<extra) f=1; eq++; }
    else if (v>T) f=1;
    if (f){
      int n = tid*16 + e;
      outIdxF[(size_t)b*KSEL + pos] = (float)n;
      selIdx[(size_t)b*KSEL + pos] = n;
      pos++;
    }
  }
}

// ---------------------------------------------------------------------------
// Gather selected rows.
// ---------------------------------------------------------------------------
__global__ __launch_bounds__(256) void gather_kernel(
    const float* __restrict__ feat, const int* __restrict__ selIdx,
    float* __restrict__ outSel)
{
  const int tid = threadIdx.x;
  const int row = blockIdx.x*2 + (tid>>7);
  const int c4 = tid & 127;
  const int b = row / KSEL;
  const int idx = selIdx[row];
  const float4 v = *reinterpret_cast<const float4*>(feat + ((size_t)b*NP + idx)*DD + c4*4);
  *reinterpret_cast<float4*>(outSel + (size_t)row*DD + c4*4) = v;
}

// ---------------------------------------------------------------------------
// Per-(b,c) top-8/bottom-8 with lax.top_k tie semantics.
// ---------------------------------------------------------------------------
__global__ __launch_bounds__(256) void top16_kernel(
    const float* __restrict__ attn, int* __restrict__ top16)
{
  __shared__ unsigned long long keys[2048];
  __shared__ unsigned long long red[4];
  __shared__ unsigned long long gkey;
  const int tid = threadIdx.x;
  const int bid = blockIdx.x;
  const int lane = tid & 63, wid = tid >> 6;
  const float* a = attn + (size_t)bid*NP;

  // ---- local top-8 (desc), key = (bits<<32) | (NP-1-n)
  unsigned long long t8[8];
  #pragma unroll
  for (int i=0;i<8;++i) t8[i]=0ull;
  for (int j=0;j<64;++j){
    int n = tid + 256*j;
    unsigned long long key = ((unsigned long long)__float_as_uint(a[n])<<32) | (unsigned)(NP-1-n);
    if (key > t8[7]){
      t8[7]=key;
      #pragma unroll
      for (int i=7;i>0;--i){ if (t8[i]>t8[i-1]){ unsigned long long t=t8[i-1]; t8[i-1]=t8[i]; t8[i]=t; } }
    }
  }
  #pragma unroll
  for (int i=0;i<8;++i) keys[tid*8+i]=t8[i];
  __syncthreads();
  for (int pick=0; pick<8; ++pick){
    unsigned long long loc = 0ull;
    #pragma unroll
    for (int i=0;i<8;++i){ unsigned long long k=keys[tid*8+i]; loc = k>loc?k:loc; }
    #pragma unroll
    for (int off=1; off<64; off<<=1){ unsigned long long o=__shfl_xor(loc,off); loc=o>loc?o:loc; }
    if (lane==0) red[wid]=loc;
    __syncthreads();
    if (tid==0){
      unsigned long long m=red[0];
      for (int w=1;w<4;++w) m = red[w]>m?red[w]:m;
      gkey=m;
      top16[bid*16+pick] = NP-1-(int)(m & 0xFFFFFFFFull);
    }
    __syncthreads();
    unsigned long long g = gkey;
    #pragma unroll
    for (int i=0;i<8;++i) if (keys[tid*8+i]==g) keys[tid*8+i]=0ull;
    __syncthreads();
  }
  // ---- local bottom-8 (asc), key = (bits<<32) | n
  unsigned long long b8[8];
  #pragma unroll
  for (int i=0;i<8;++i) b8[i]=~0ull;
  for (int j=0;j<64;++j){
    int n = tid + 256*j;
    unsigned long long key = ((unsigned long long)__float_as_uint(a[n])<<32) | (unsigned)n;
    if (key < b8[7]){
      b8[7]=key;
      #pragma unroll
      for (int i=7;i>0;--i){ if (b8[i]<b8[i-1]){ unsigned long long t=b8[i-1]; b8[i-1]=b8[i]; b8[i]=t; } }
    }
  }
  __syncthreads();
  #pragma unroll
  for (int i=0;i<8;++i) keys[tid*8+i]=b8[i];
  __syncthreads();
  for (int pick=8; pick<16; ++pick){
    unsigned long long loc = ~0ull;
    #pragma unroll
    for (int i=0;i<8;++i){ unsigned long long k=keys[tid*8+i]; loc = k<loc?k:loc; }
    #pragma unroll
    for (int off=1; off<64; off<<=1){ unsigned long long o=__shfl_xor(loc,off); loc=o<loc?o:loc; }
    if (lane==0) red[wid]=loc;
    __syncthreads();
    if (tid==0){
      unsigned long long m=red[0];
      for (int w=1;w<4;++w) m = red[w]<m?red[w]:m;
      gkey=m;
      top16[bid*16+pick] = (int)(m & 0xFFFFFFFFull);
    }
    __syncthreads();
    unsigned long long g = gkey;
    #pragma unroll
    for (int i=0;i<8;++i) if (keys[tid*8+i]==g) keys[tid*8+i]=~0ull;
    __syncthreads();
  }
}

// ---------------------------------------------------------------------------
// Instance MLP + CE partial, one block per (b,c,r).
// ---------------------------------------------------------------------------
__global__ __launch_bounds__(256) void mlp_kernel(
    const float* __restrict__ feat, const float* __restrict__ W1,
    const float* __restrict__ b1, const float* __restrict__ W2,
    const float* __restrict__ b2, const int* __restrict__ top16,
    float* __restrict__ cews)
{
  __shared__ float fS[DD];
  __shared__ float r0[4], r1[4];
  const int tid = threadIdx.x;
  const int bid = blockIdx.x;
  const int r = bid & 15, c = (bid >> 4) & 1, b = bid >> 5;
  const int lane = tid & 63, wid = tid >> 6;
  const int gi = top16[(b*2+c)*16 + r];
  if (tid < 128){
    float4 v = *reinterpret_cast<const float4*>(feat + ((size_t)b*NP + gi)*DD + tid*4);
    *reinterpret_cast<float4*>(&fS[tid*4]) = v;
  }
  __syncthreads();
  const float* w1c = W1 + (size_t)c*DD*HH;
  float a0=0.f,a1=0.f,a2=0.f,a3=0.f;
  #pragma unroll 4
  for (int d=0; d<DD; d+=4){
    a0 += fS[d+0]*w1c[(size_t)(d+0)*HH + tid];
    a1 += fS[d+1]*w1c[(size_t)(d+1)*HH + tid];
    a2 += fS[d+2]*w1c[(size_t)(d+2)*HH + tid];
    a3 += fS[d+3]*w1c[(size_t)(d+3)*HH + tid];
  }
  float h = fmaxf((a0+a1)+(a2+a3) + b1[c*HH+tid], 0.f);
  float p0 = h*W2[(size_t)(c*HH+tid)*2 + 0];
  float p1 = h*W2[(size_t)(c*HH+tid)*2 + 1];
  #pragma unroll
  for (int off=1; off<64; off<<=1){ p0+=__shfl_xor(p0,off); p1+=__shfl_xor(p1,off); }
  if (lane==0){ r0[wid]=p0; r1[wid]=p1; }
  __syncthreads();
  if (tid==0){
    float l0 = (r0[0]+r0[1])+(r0[2]+r0[3]) + b2[c*2+0];
    float l1 = (r1[0]+r1[1])+(r1[2]+r1[3]) + b2[c*2+1];
    float mm = fmaxf(l0,l1);
    float lse = mm + logf(expf(l0-mm)+expf(l1-mm));
    float chosen = (r<8) ? l1 : l0;
    cews[bid] = lse - chosen;
  }
}

__global__ void loss_kernel(const float* __restrict__ cews, float* __restrict__ out_loss){
  if (threadIdx.x==0 && blockIdx.x==0){
    float s=0.f;
    for (int i=0;i<128;++i) s += cews[i];
    out_loss[0] = s / 128.0f;
  }
}

extern "C" void kernel_launch(void* const* d_in, const int* in_sizes, int n_in,
                              void* d_out, int out_size, void* d_ws, size_t ws_size,
                              hipStream_t stream) {
  const float* feat = (const float*)d_in[0];
  const float* Wa   = (const float*)d_in[1];
  const float* ba   = (const float*)d_in[2];
  const float* Wbr  = (const float*)d_in[3];
  const float* bbr  = (const float*)d_in[4];
  const float* W1   = (const float*)d_in[5];
  const float* b1   = (const float*)d_in[6];
  const float* W2   = (const float*)d_in[7];
  const float* b2   = (const float*)d_in[8];
  float* out = (float*)d_out;
  float* ws  = (float*)d_ws;

  float* a_logits = ws + WS_ALOGIT;
  float* attn     = ws + WS_ATTN;
  int*   selIdx   = (int*)(ws + WS_SELIDX);
  float* mz       = ws + WS_MZ;
  int*   bcnt     = (int*)(ws + WS_BCNT);
  int*   blist    = (int*)(ws + WS_BLIST);
  int*   top16    = (int*)(ws + WS_TOP16);
  float* cews     = ws + WS_CE;

  unsigned short* WaT = (unsigned short*)d_out;   // head of selected region;
                                                  // fully overwritten by gather

  hipLaunchKernelGGL(waconv_kernel, dim3(DD/32, HH/32), dim3(32,8), 0, stream,
                     Wa, WaT);
  hipLaunchKernelGGL(gemm_mfma_kernel, dim3(TOTP/128), dim3(512), 0, stream,
                     feat, WaT, ba, Wbr, bbr, a_logits);
  hipLaunchKernelGGL(softmax2_kernel, dim3(NB), dim3(1024), 0, stream,
                     a_logits, attn, out + OFF_COMB, mz);
  hipLaunchKernelGGL(selT_kernel, dim3(NB), dim3(1024), 0, stream,
                     out + OFF_COMB, bcnt, blist);
  hipLaunchKernelGGL(recomp_kernel, dim3(NB*64), dim3(256), 0, stream,
                     feat, Wa, ba, Wbr, bbr, mz, bcnt, blist, out + OFF_COMB);
  hipLaunchKernelGGL(select_kernel, dim3(NB), dim3(1024), 0, stream,
                     out + OFF_COMB, out + OFF_IDX, selIdx);
  hipLaunchKernelGGL(gather_kernel, dim3(NB*KSEL/2), dim3(256), 0, stream,
                     feat, selIdx, out);
  hipLaunchKernelGGL(top16_kernel, dim3(NB*CC), dim3(256), 0, stream,
                     attn, top16);
  hipLaunchKernelGGL(mlp_kernel, dim3(NB*CC*16), dim3(256), 0, stream,
                     feat, W1, b1, W2, b2, top16, cews);
  hipLaunchKernelGGL(loss_kernel, dim3(1), dim3(64), 0, stream,
                     cews, out + OFF_LOSS);
}

// Round 3
// 298.542 us; speedup vs baseline: 1.5862x; 1.1939x over previous
//
#include <hip/hip_runtime.h>

#define NB 4
#define NP 16384
#define DD 512
#define HH 256
#define CC 2
#define KSEL 11468
#define TOTP (NB*NP)
#define BCAP 4096

// d_out offsets (floats)
#define OFF_COMB (NB*KSEL*DD)            // 23486464
#define OFF_IDX  (OFF_COMB + NB*NP)      // 23552000
#define OFF_LOSS (OFF_IDX + NB*KSEL)     // 23597872

// ws offsets (floats)
#define WS_ALOGIT 0
#define WS_ATTN   (NB*CC*NP)                 // 131072
#define WS_SELIDX (2*NB*CC*NP)               // 262144 (ints)
#define WS_MZ     (WS_SELIDX + NB*KSEL)      // 308016 (16 floats)
#define WS_BCNT   (WS_MZ + 16)               // ints (4)
#define WS_BLIST  (WS_BCNT + 4)              // ints (4*BCAP)
#define WS_TOP16  (WS_BLIST + NB*BCAP)       // ints (8*16)
#define WS_CE     (WS_TOP16 + 128)           // floats (128)

typedef __attribute__((ext_vector_type(8))) short short8x;
typedef __attribute__((ext_vector_type(4))) float f32x4;

__device__ __forceinline__ unsigned short f2bf(float x){
  unsigned u = __float_as_uint(x);
  unsigned r = (u + 0x7FFFu + ((u >> 16) & 1u)) >> 16;
  return (unsigned short)r;
}

// ---------------------------------------------------------------------------
// Wa (512x256 f32) -> Wa_t (256x512 bf16), transposed, stored at d_out head.
// ---------------------------------------------------------------------------
__global__ __launch_bounds__(256) void waconv_kernel(
    const float* __restrict__ Wa, unsigned short* __restrict__ WaT)
{
  __shared__ float tile[32][33];
  const int tx = threadIdx.x, ty = threadIdx.y;   // 32 x 8
  const int k0 = blockIdx.x * 32, n0 = blockIdx.y * 32;
  #pragma unroll
  for (int i=0;i<4;++i)
    tile[ty+8*i][tx] = Wa[(size_t)(k0+ty+8*i)*HH + n0 + tx];
  __syncthreads();
  #pragma unroll
  for (int i=0;i<4;++i)
    WaT[(size_t)(n0+ty+8*i)*DD + k0 + tx] = f2bf(tile[tx][ty+8*i]);
}

// ---------------------------------------------------------------------------
// MFMA GEMM: a_logits[b,c,n] = Wbr[c].relu(f[n]@Wa+ba) + bbr[c], bf16 inputs.
// BM=128, BN=256(full H), BK=64; 8 waves (2M x 4N), wave tile 64x64.
// ---------------------------------------------------------------------------
__global__ __launch_bounds__(512) void gemm_mfma_kernel(
    const float* __restrict__ feat, const unsigned short* __restrict__ WaT,
    const float* __restrict__ ba, const float* __restrict__ Wbr,
    const float* __restrict__ bbr, float* __restrict__ aL)
{
  __shared__ __attribute__((aligned(16))) unsigned char smem[65536];
  __shared__ float sBA[HH], sW0[HH], sW1[HH];
  unsigned char* sA = smem;                 // 128*64 bf16 = 16 KB (swizzled)
  unsigned char* sB = smem + 16384;         // 256*64 bf16 = 32 KB (swizzled)

  const int tid  = threadIdx.x;
  const int lane = tid & 63;
  const int wid  = tid >> 6;
  const int wm = wid >> 2, wn = wid & 3;
  const int fr = lane & 15, fq = lane >> 4;
  const int p0 = blockIdx.x * 128;
  const float bb0 = bbr[0], bb1 = bbr[1];

  if (tid < HH){ sBA[tid] = ba[tid]; sW0[tid] = Wbr[tid]; sW1[tid] = Wbr[HH+tid]; }

  f32x4 acc[4][4];
  #pragma unroll
  for (int i=0;i<4;++i)
    #pragma unroll
    for (int j=0;j<4;++j)
      acc[i][j] = (f32x4){0.f,0.f,0.f,0.f};

  const int am = tid >> 2, akq = (tid & 3) * 16;     // A staging: row, k-offset
  const int bn = tid >> 1, bhf = tid & 1;            // B staging

  for (int k0 = 0; k0 < DD; k0 += 64){
    __syncthreads();
    // ---- stage A: 128x64 fp32 -> bf16, swizzled K-major
    {
      const float4* src = reinterpret_cast<const float4*>(
          feat + (size_t)(p0 + am)*DD + k0 + akq);
      float4 v0 = src[0], v1 = src[1], v2 = src[2], v3 = src[3];
      unsigned short u[16];
      u[0]=f2bf(v0.x); u[1]=f2bf(v0.y); u[2]=f2bf(v0.z); u[3]=f2bf(v0.w);
      u[4]=f2bf(v1.x); u[5]=f2bf(v1.y); u[6]=f2bf(v1.z); u[7]=f2bf(v1.w);
      u[8]=f2bf(v2.x); u[9]=f2bf(v2.y); u[10]=f2bf(v2.z); u[11]=f2bf(v2.w);
      u[12]=f2bf(v3.x); u[13]=f2bf(v3.y); u[14]=f2bf(v3.z); u[15]=f2bf(v3.w);
      uint4 w0, w1;
      w0.x = (unsigned)u[0] | ((unsigned)u[1]<<16);
      w0.y = (unsigned)u[2] | ((unsigned)u[3]<<16);
      w0.z = (unsigned)u[4] | ((unsigned)u[5]<<16);
      w0.w = (unsigned)u[6] | ((unsigned)u[7]<<16);
      w1.x = (unsigned)u[8] | ((unsigned)u[9]<<16);
      w1.y = (unsigned)u[10] | ((unsigned)u[11]<<16);
      w1.z = (unsigned)u[12] | ((unsigned)u[13]<<16);
      w1.w = (unsigned)u[14] | ((unsigned)u[15]<<16);
      const int swz = (am & 7) << 4;
      *reinterpret_cast<uint4*>(sA + (((am*128) + akq*2) ^ swz)) = w0;
      *reinterpret_cast<uint4*>(sA + (((am*128) + akq*2 + 16) ^ swz)) = w1;
    }
    // ---- stage B: 256x64 bf16 from WaT, swizzled K-major
    {
      const uint4* src = reinterpret_cast<const uint4*>(
          WaT + (size_t)bn*DD + k0 + bhf*32);
      uint4 q0 = src[0], q1 = src[1], q2 = src[2], q3 = src[3];
      const int swz = (bn & 7) << 4;
      const int base = bn*128 + bhf*64;
      *reinterpret_cast<uint4*>(sB + ((base     ) ^ swz)) = q0;
      *reinterpret_cast<uint4*>(sB + ((base + 16) ^ swz)) = q1;
      *reinterpret_cast<uint4*>(sB + ((base + 32) ^ swz)) = q2;
      *reinterpret_cast<uint4*>(sB + ((base + 48) ^ swz)) = q3;
    }
    __syncthreads();
    // ---- MFMA
    #pragma unroll
    for (int kf = 0; kf < 2; ++kf){
      short8x af[4], bf[4];
      #pragma unroll
      for (int mf = 0; mf < 4; ++mf){
        int m_loc = wm*64 + mf*16 + fr;
        int off = ((m_loc*128 + kf*64 + fq*16) ^ ((m_loc & 7) << 4));
        af[mf] = *reinterpret_cast<const short8x*>(sA + off);
      }
      #pragma unroll
      for (int nf = 0; nf < 4; ++nf){
        int n_loc = wn*64 + nf*16 + fr;
        int off = ((n_loc*128 + kf*64 + fq*16) ^ ((n_loc & 7) << 4));
        bf[nf] = *reinterpret_cast<const short8x*>(sB + off);
      }
      #pragma unroll
      for (int mf = 0; mf < 4; ++mf)
        #pragma unroll
        for (int nf = 0; nf < 4; ++nf)
          acc[mf][nf] = __builtin_amdgcn_mfma_f32_16x16x32_bf16(
              af[mf], bf[nf], acc[mf][nf], 0, 0, 0);
    }
  }
  __syncthreads();

  // ---- epilogue: relu + Wbr projection via LDS h-tile, M in halves of 64
  float* hS = reinterpret_cast<float*>(smem);
  #pragma unroll
  for (int mh = 0; mh < 2; ++mh){
    if (wm == mh){
      #pragma unroll
      for (int mf = 0; mf < 4; ++mf)
        #pragma unroll
        for (int nf = 0; nf < 4; ++nf)
          #pragma unroll
          for (int r = 0; r < 4; ++r){
            int row = mf*16 + fq*4 + r;
            int col = wn*64 + nf*16 + fr;
            hS[row*256 + col] = acc[mf][nf][r];
          }
    }
    __syncthreads();
    {
      const int row = tid >> 3, cg = tid & 7;
      float s0 = 0.f, s1 = 0.f;
      #pragma unroll
      for (int j = 0; j < 8; ++j){
        int col = cg*4 + j*32;
        float4 hv = *reinterpret_cast<const float4*>(&hS[row*256 + col]);
        float xs[4] = {hv.x, hv.y, hv.z, hv.w};
        #pragma unroll
        for (int u = 0; u < 4; ++u){
          int ccol = col + u;
          float x = fmaxf(xs[u] + sBA[ccol], 0.f);
          s0 += x * sW0[ccol];
          s1 += x * sW1[ccol];
        }
      }
      s0 += __shfl_xor(s0,1); s1 += __shfl_xor(s1,1);
      s0 += __shfl_xor(s0,2); s1 += __shfl_xor(s1,2);
      s0 += __shfl_xor(s0,4); s1 += __shfl_xor(s1,4);
      if (cg == 0){
        int p = p0 + mh*64 + row;
        int b = p >> 14, nl = p & (NP-1);
        aL[((size_t)b*CC + 0)*NP + nl] = s0 + bb0;
        aL[((size_t)b*CC + 1)*NP + nl] = s1 + bb1;
      }
    }
    __syncthreads();
  }
}

// ---------------------------------------------------------------------------
// Softmax both classes + combined, store m and 1/Z per (b,c) for refinement.
// ---------------------------------------------------------------------------
__global__ __launch_bounds__(1024) void softmax2_kernel(
    const float* __restrict__ aL, float* __restrict__ attn,
    float* __restrict__ comb, float* __restrict__ mz)
{
  __shared__ float  s_redf[16];
  __shared__ double s_redd[16];
  __shared__ float  s_m[2];
  __shared__ float  s_iz[2];
  const int tid = threadIdx.x;
  const int lane = tid & 63, wid = tid >> 6;
  const int b = blockIdx.x;

  #pragma unroll
  for (int c = 0; c < 2; ++c){
    const float* a = aL + ((size_t)b*CC + c)*NP;
    float m = -1e30f;
    for (int n = tid; n < NP; n += 1024) m = fmaxf(m, a[n]);
    #pragma unroll
    for (int off=1; off<64; off<<=1) m = fmaxf(m, __shfl_xor(m, off));
    if (lane==0) s_redf[wid] = m;
    __syncthreads();
    if (tid==0){ float mm=s_redf[0]; for(int w=1;w<16;++w) mm=fmaxf(mm,s_redf[w]); s_m[c]=mm; }
    __syncthreads();
    m = s_m[c];
    double ls = 0.0;
    for (int n = tid; n < NP; n += 1024) ls += (double)expf(a[n]-m);
    #pragma unroll
    for (int off=1; off<64; off<<=1) ls += __shfl_xor(ls, off);
    if (lane==0) s_redd[wid] = ls;
    __syncthreads();
    if (tid==0){ double t=0; for(int w=0;w<16;++w) t+=s_redd[w]; s_iz[c]=(float)(1.0/t); }
    __syncthreads();
  }
  const float m0 = s_m[0], iz0 = s_iz[0], m1 = s_m[1], iz1 = s_iz[1];
  const float* a0 = aL + ((size_t)b*CC + 0)*NP;
  const float* a1 = aL + ((size_t)b*CC + 1)*NP;
  float* o0 = attn + ((size_t)b*CC + 0)*NP;
  float* o1 = attn + ((size_t)b*CC + 1)*NP;
  float* oc = comb + (size_t)b*NP;
  for (int n = tid; n < NP; n += 1024){
    float e0 = expf(a0[n]-m0)*iz0;
    float e1 = expf(a1[n]-m1)*iz1;
    o0[n] = e0; o1[n] = e1; oc[n] = 0.5f*(e0+e1);
  }
  if (tid==0){ mz[b*4+0]=m0; mz[b*4+1]=iz0; mz[b*4+2]=m1; mz[b*4+3]=iz1; }
}

// ---------------------------------------------------------------------------
// Approximate threshold (top 20 bits) + band list for refinement.
// ---------------------------------------------------------------------------
#define SKW 1028
__global__ __launch_bounds__(1024) void selT_kernel(
    const float* __restrict__ comb, int* __restrict__ bcnt,
    int* __restrict__ blist)
{
  __shared__ unsigned s_bits[16*SKW];
  __shared__ unsigned s_red[16];
  __shared__ unsigned s_bcast;
  __shared__ int s_cnt;
  const int tid = threadIdx.x;
  const int b = blockIdx.x;
  const int lane = tid & 63, wid = tid >> 6;
  const float* row = comb + (size_t)b*NP;
  for (int j=0;j<16;++j){
    int n = tid + j*1024;
    s_bits[(n & 15)*SKW + (n >> 4)] = __float_as_uint(row[n]);
  }
  if (tid==0) s_cnt = 0;
  __syncthreads();
  unsigned cur = 0;
  for (int bit=31; bit>=12; --bit){
    unsigned trial = cur | (1u<<bit);
    int c = 0;
    #pragma unroll
    for (int j=0;j<16;++j) c += (s_bits[j*SKW + tid] >= trial) ? 1 : 0;
    #pragma unroll
    for (int off=1; off<64; off<<=1) c += __shfl_xor(c, off);
    if (lane==0) s_red[wid] = (unsigned)c;
    __syncthreads();
    if (tid==0){ unsigned t=0; for(int w=0;w<16;++w) t+=s_red[w]; s_bcast=t; }
    __syncthreads();
    if (s_bcast >= KSEL) cur = trial;
    __syncthreads();
  }
  const float Tv = __uint_as_float(cur);
  const float lo = Tv*0.989f, hi = Tv*1.0115f;
  #pragma unroll
  for (int e=0;e<16;++e){
    float v = __uint_as_float(s_bits[e*SKW + tid]);
    if (v >= lo && v <= hi){
      int s = atomicAdd(&s_cnt, 1);
      if (s < BCAP) blist[b*BCAP + s] = tid*16 + e;
    }
  }
  __syncthreads();
  if (tid==0) bcnt[b] = (s_cnt < BCAP) ? s_cnt : BCAP;
}

// ---------------------------------------------------------------------------
// Exact fp32 recompute of combined for band members.
// One block per candidate slot: grid = NB*BCAP, inactive blocks exit.
// ---------------------------------------------------------------------------
__global__ __launch_bounds__(256) void recomp_kernel(
    const float* __restrict__ feat, const float* __restrict__ Wa,
    const float* __restrict__ ba, const float* __restrict__ Wbr,
    const float* __restrict__ bbr, const float* __restrict__ mz,
    const int* __restrict__ bcnt, const int* __restrict__ blist,
    float* __restrict__ comb)
{
  __shared__ float fS[DD];
  __shared__ float r0[4], r1[4];
  const int tid = threadIdx.x;
  const int b = blockIdx.x >> 12;          // BCAP = 4096 slots per batch
  const int s = blockIdx.x & (BCAP-1);
  if (s >= bcnt[b]) return;
  const int lane = tid & 63, wid = tid >> 6;
  const float m0 = mz[b*4+0], iz0 = mz[b*4+1], m1 = mz[b*4+2], iz1 = mz[b*4+3];
  const int n = blist[b*BCAP + s];
  if (tid < 128){
    float4 v = *reinterpret_cast<const float4*>(feat + ((size_t)b*NP + n)*DD + tid*4);
    *reinterpret_cast<float4*>(&fS[tid*4]) = v;
  }
  __syncthreads();
  float a0=0.f,a1=0.f,a2=0.f,a3=0.f;
  #pragma unroll 4
  for (int d=0; d<DD; d+=4){
    a0 += fS[d+0]*Wa[(size_t)(d+0)*HH + tid];
    a1 += fS[d+1]*Wa[(size_t)(d+1)*HH + tid];
    a2 += fS[d+2]*Wa[(size_t)(d+2)*HH + tid];
    a3 += fS[d+3]*Wa[(size_t)(d+3)*HH + tid];
  }
  float h = fmaxf((a0+a1)+(a2+a3) + ba[tid], 0.f);
  float p0 = h*Wbr[tid], p1 = h*Wbr[HH+tid];
  #pragma unroll
  for (int off=1; off<64; off<<=1){ p0+=__shfl_xor(p0,off); p1+=__shfl_xor(p1,off); }
  if (lane==0){ r0[wid]=p0; r1[wid]=p1; }
  __syncthreads();
  if (tid==0){
    float l0 = (r0[0]+r0[1])+(r0[2]+r0[3]) + bbr[0];
    float l1 = (r1[0]+r1[1])+(r1[2]+r1[3]) + bbr[1];
    comb[(size_t)b*NP + n] = 0.5f*(expf(l0-m0)*iz0 + expf(l1-m1)*iz1);
  }
}

// ---------------------------------------------------------------------------
// Exact top-k selection on refined combined (round-1 proven kernel).
// ---------------------------------------------------------------------------
__global__ __launch_bounds__(1024) void select_kernel(
    const float* __restrict__ comb, float* __restrict__ outIdxF,
    int* __restrict__ selIdx)
{
  __shared__ unsigned s_bits[16*SKW];
  __shared__ unsigned s_red[16];
  __shared__ unsigned s_scan[1024];
  __shared__ unsigned s_bcast;
  const int tid = threadIdx.x;
  const int b = blockIdx.x;
  const int lane = tid & 63, wid = tid >> 6;
  const float* row = comb + (size_t)b*NP;
  for (int j=0;j<16;++j){
    int n = tid + j*1024;
    s_bits[(n & 15)*SKW + (n >> 4)] = __float_as_uint(row[n]);
  }
  __syncthreads();
  unsigned cur = 0;
  for (int bit=31; bit>=0; --bit){
    unsigned trial = cur | (1u<<bit);
    int c = 0;
    #pragma unroll
    for (int j=0;j<16;++j) c += (s_bits[j*SKW + tid] >= trial) ? 1 : 0;
    #pragma unroll
    for (int off=1; off<64; off<<=1) c += __shfl_xor(c, off);
    if (lane==0) s_red[wid] = (unsigned)c;
    __syncthreads();
    if (tid==0){ unsigned t=0; for(int w=0;w<16;++w) t+=s_red[w]; s_bcast=t; }
    __syncthreads();
    if (s_bcast >= KSEL) cur = trial;
    __syncthreads();
  }
  const unsigned T = cur;
  {
    int c = 0;
    #pragma unroll
    for (int j=0;j<16;++j) c += (s_bits[j*SKW + tid] > T) ? 1 : 0;
    #pragma unroll
    for (int off=1; off<64; off<<=1) c += __shfl_xor(c, off);
    if (lane==0) s_red[wid] = (unsigned)c;
    __syncthreads();
    if (tid==0){ unsigned t=0; for(int w=0;w<16;++w) t+=s_red[w]; s_bcast=t; }
    __syncthreads();
  }
  const int extra = KSEL - (int)s_bcast;
  __syncthreads();
  int eqc=0;
  #pragma unroll
  for (int e=0;e<16;++e) eqc += (s_bits[e*SKW + tid]==T) ? 1 : 0;
  s_scan[tid]=(unsigned)eqc;
  __syncthreads();
  for (int off=1; off<1024; off<<=1){
    unsigned v = (tid>=off)? s_scan[tid-off] : 0u;
    __syncthreads();
    s_scan[tid]+=v;
    __syncthreads();
  }
  const int eqBase = (int)s_scan[tid] - eqc;
  __syncthreads();
  int eq=eqBase, sc=0;
  #pragma unroll
  for (int e=0;e<16;++e){
    unsigned v = s_bits[e*SKW + tid];
    if (v==T){ if (eq<extra) sc++; eq++; }
    else if (v>T) sc++;
  }
  s_scan[tid]=(unsigned)sc;
  __syncthreads();
  for (int off=1; off<1024; off<<=1){
    unsigned v = (tid>=off)? s_scan[tid-off] : 0u;
    __syncthreads();
    s_scan[tid]+=v;
    __syncthreads();
  }
  int pos = (int)s_scan[tid] - sc;
  eq=eqBase;
  #pragma unroll
  for (int e=0;e<16;++e){
    unsigned v = s_bits[e*SKW + tid];
    int f=0;
    if (v==T){ if (eq<extra) f=1; eq++; }
    else if (v>T) f=1;
    if (f){
      int n = tid*16 + e;
      outIdxF[(size_t)b*KSEL + pos] = (float)n;
      selIdx[(size_t)b*KSEL + pos] = n;
      pos++;
    }
  }
}

// ---------------------------------------------------------------------------
// Gather selected rows.
// ---------------------------------------------------------------------------
__global__ __launch_bounds__(256) void gather_kernel(
    const float* __restrict__ feat, const int* __restrict__ selIdx,
    float* __restrict__ outSel)
{
  const int tid = threadIdx.x;
  const int row = blockIdx.x*2 + (tid>>7);
  const int c4 = tid & 127;
  const int b = row / KSEL;
  const int idx = selIdx[row];
  const float4 v = *reinterpret_cast<const float4*>(feat + ((size_t)b*NP + idx)*DD + c4*4);
  *reinterpret_cast<float4*>(outSel + (size_t)row*DD + c4*4) = v;
}

// ---------------------------------------------------------------------------
// Per-(b,c) top-8/bottom-8 with lax.top_k tie semantics.
// ---------------------------------------------------------------------------
__global__ __launch_bounds__(256) void top16_kernel(
    const float* __restrict__ attn, int* __restrict__ top16)
{
  __shared__ unsigned long long keys[2048];
  __shared__ unsigned long long red[4];
  __shared__ unsigned long long gkey;
  const int tid = threadIdx.x;
  const int bid = blockIdx.x;
  const int lane = tid & 63, wid = tid >> 6;
  const float* a = attn + (size_t)bid*NP;

  // ---- local top-8 (desc), key = (bits<<32) | (NP-1-n)
  unsigned long long t8[8];
  #pragma unroll
  for (int i=0;i<8;++i) t8[i]=0ull;
  for (int j=0;j<64;++j){
    int n = tid + 256*j;
    unsigned long long key = ((unsigned long long)__float_as_uint(a[n])<<32) | (unsigned)(NP-1-n);
    if (key > t8[7]){
      t8[7]=key;
      #pragma unroll
      for (int i=7;i>0;--i){ if (t8[i]>t8[i-1]){ unsigned long long t=t8[i-1]; t8[i-1]=t8[i]; t8[i]=t; } }
    }
  }
  #pragma unroll
  for (int i=0;i<8;++i) keys[tid*8+i]=t8[i];
  __syncthreads();
  for (int pick=0; pick<8; ++pick){
    unsigned long long loc = 0ull;
    #pragma unroll
    for (int i=0;i<8;++i){ unsigned long long k=keys[tid*8+i]; loc = k>loc?k:loc; }
    #pragma unroll
    for (int off=1; off<64; off<<=1){ unsigned long long o=__shfl_xor(loc,off); loc=o>loc?o:loc; }
    if (lane==0) red[wid]=loc;
    __syncthreads();
    if (tid==0){
      unsigned long long m=red[0];
      for (int w=1;w<4;++w) m = red[w]>m?red[w]:m;
      gkey=m;
      top16[bid*16+pick] = NP-1-(int)(m & 0xFFFFFFFFull);
    }
    __syncthreads();
    unsigned long long g = gkey;
    #pragma unroll
    for (int i=0;i<8;++i) if (keys[tid*8+i]==g) keys[tid*8+i]=0ull;
    __syncthreads();
  }
  // ---- local bottom-8 (asc), key = (bits<<32) | n
  unsigned long long b8[8];
  #pragma unroll
  for (int i=0;i<8;++i) b8[i]=~0ull;
  for (int j=0;j<64;++j){
    int n = tid + 256*j;
    unsigned long long key = ((unsigned long long)__float_as_uint(a[n])<<32) | (unsigned)n;
    if (key < b8[7]){
      b8[7]=key;
      #pragma unroll
      for (int i=7;i>0;--i){ if (b8[i]<b8[i-1]){ unsigned long long t=b8[i-1]; b8[i-1]=b8[i]; b8[i]=t; } }
    }
  }
  __syncthreads();
  #pragma unroll
  for (int i=0;i<8;++i) keys[tid*8+i]=b8[i];
  __syncthreads();
  for (int pick=8; pick<16; ++pick){
    unsigned long long loc = ~0ull;
    #pragma unroll
    for (int i=0;i<8;++i){ unsigned long long k=keys[tid*8+i]; loc = k<loc?k:loc; }
    #pragma unroll
    for (int off=1; off<64; off<<=1){ unsigned long long o=__shfl_xor(loc,off); loc=o<loc?o:loc; }
    if (lane==0) red[wid]=loc;
    __syncthreads();
    if (tid==0){
      unsigned long long m=red[0];
      for (int w=1;w<4;++w) m = red[w]<m?red[w]:m;
      gkey=m;
      top16[bid*16+pick] = (int)(m & 0xFFFFFFFFull);
    }
    __syncthreads();
    unsigned long long g = gkey;
    #pragma unroll
    for (int i=0;i<8;++i) if (keys[tid*8+i]==g) keys[tid*8+i]=~0ull;
    __syncthreads();
  }
}

// ---------------------------------------------------------------------------
// Instance MLP + CE partial, one block per (b,c,r).
// ---------------------------------------------------------------------------
__global__ __launch_bounds__(256) void mlp_kernel(
    const float* __restrict__ feat, const float* __restrict__ W1,
    const float* __restrict__ b1, const float* __restrict__ W2,
    const float* __restrict__ b2, const int* __restrict__ top16,
    float* __restrict__ cews)
{
  __shared__ float fS[DD];
  __shared__ float r0[4], r1[4];
  const int tid = threadIdx.x;
  const int bid = blockIdx.x;
  const int r = bid & 15, c = (bid >> 4) & 1, b = bid >> 5;
  const int lane = tid & 63, wid = tid >> 6;
  const int gi = top16[(b*2+c)*16 + r];
  if (tid < 128){
    float4 v = *reinterpret_cast<const float4*>(feat + ((size_t)b*NP + gi)*DD + tid*4);
    *reinterpret_cast<float4*>(&fS[tid*4]) = v;
  }
  __syncthreads();
  const float* w1c = W1 + (size_t)c*DD*HH;
  float a0=0.f,a1=0.f,a2=0.f,a3=0.f;
  #pragma unroll 4
  for (int d=0; d<DD; d+=4){
    a0 += fS[d+0]*w1c[(size_t)(d+0)*HH + tid];
    a1 += fS[d+1]*w1c[(size_t)(d+1)*HH + tid];
    a2 += fS[d+2]*w1c[(size_t)(d+2)*HH + tid];
    a3 += fS[d+3]*w1c[(size_t)(d+3)*HH + tid];
  }
  float h = fmaxf((a0+a1)+(a2+a3) + b1[c*HH+tid], 0.f);
  float p0 = h*W2[(size_t)(c*HH+tid)*2 + 0];
  float p1 = h*W2[(size_t)(c*HH+tid)*2 + 1];
  #pragma unroll
  for (int off=1; off<64; off<<=1){ p0+=__shfl_xor(p0,off); p1+=__shfl_xor(p1,off); }
  if (lane==0){ r0[wid]=p0; r1[wid]=p1; }
  __syncthreads();
  if (tid==0){
    float l0 = (r0[0]+r0[1])+(r0[2]+r0[3]) + b2[c*2+0];
    float l1 = (r1[0]+r1[1])+(r1[2]+r1[3]) + b2[c*2+1];
    float mm = fmaxf(l0,l1);
    float lse = mm + logf(expf(l0-mm)+expf(l1-mm));
    float chosen = (r<8) ? l1 : l0;
    cews[bid] = lse - chosen;
  }
}

__global__ void loss_kernel(const float* __restrict__ cews, float* __restrict__ out_loss){
  if (threadIdx.x==0 && blockIdx.x==0){
    float s=0.f;
    for (int i=0;i<128;++i) s += cews[i];
    out_loss[0] = s / 128.0f;
  }
}

extern "C" void kernel_launch(void* const* d_in, const int* in_sizes, int n_in,
                              void* d_out, int out_size, void* d_ws, size_t ws_size,
                              hipStream_t stream) {
  const float* feat = (const float*)d_in[0];
  const float* Wa   = (const float*)d_in[1];
  const float* ba   = (const float*)d_in[2];
  const float* Wbr  = (const float*)d_in[3];
  const float* bbr  = (const float*)d_in[4];
  const float* W1   = (const float*)d_in[5];
  const float* b1   = (const float*)d_in[6];
  const float* W2   = (const float*)d_in[7];
  const float* b2   = (const float*)d_in[8];
  float* out = (float*)d_out;
  float* ws  = (float*)d_ws;

  float* a_logits = ws + WS_ALOGIT;
  float* attn     = ws + WS_ATTN;
  int*   selIdx   = (int*)(ws + WS_SELIDX);
  float* mz       = ws + WS_MZ;
  int*   bcnt     = (int*)(ws + WS_BCNT);
  int*   blist    = (int*)(ws + WS_BLIST);
  int*   top16    = (int*)(ws + WS_TOP16);
  float* cews     = ws + WS_CE;

  unsigned short* WaT = (unsigned short*)d_out;   // head of selected region;
                                                  // fully overwritten by gather

  hipLaunchKernelGGL(waconv_kernel, dim3(DD/32, HH/32), dim3(32,8), 0, stream,
                     Wa, WaT);
  hipLaunchKernelGGL(gemm_mfma_kernel, dim3(TOTP/128), dim3(512), 0, stream,
                     feat, WaT, ba, Wbr, bbr, a_logits);
  hipLaunchKernelGGL(softmax2_kernel, dim3(NB), dim3(1024), 0, stream,
                     a_logits, attn, out + OFF_COMB, mz);
  hipLaunchKernelGGL(selT_kernel, dim3(NB), dim3(1024), 0, stream,
                     out + OFF_COMB, bcnt, blist);
  hipLaunchKernelGGL(recomp_kernel, dim3(NB*BCAP), dim3(256), 0, stream,
                     feat, Wa, ba, Wbr, bbr, mz, bcnt, blist, out + OFF_COMB);
  hipLaunchKernelGGL(select_kernel, dim3(NB), dim3(1024), 0, stream,
                     out + OFF_COMB, out + OFF_IDX, selIdx);
  hipLaunchKernelGGL(gather_kernel, dim3(NB*KSEL/2), dim3(256), 0, stream,
                     feat, selIdx, out);
  hipLaunchKernelGGL(top16_kernel, dim3(NB*CC), dim3(256), 0, stream,
                     attn, top16);
  hipLaunchKernelGGL(mlp_kernel, dim3(NB*CC*16), dim3(256), 0, stream,
                     feat, W1, b1, W2, b2, top16, cews);
  hipLaunchKernelGGL(loss_kernel, dim3(1), dim3(64), 0, stream,
                     cews, out + OFF_LOSS);
}

// Round 4
// 283.749 us; speedup vs baseline: 1.6689x; 1.0521x over previous
//
#include <hip/hip_runtime.h>

#define NB 4
#define NP 16384
#define DD 512
#define HH 256
#define CC 2
#define KSEL 11468
#define TOTP (NB*NP)
#define BCAP 4096

// d_out offsets (floats)
#define OFF_COMB (NB*KSEL*DD)            // 23486464
#define OFF_IDX  (OFF_COMB + NB*NP)      // 23552000
#define OFF_LOSS (OFF_IDX + NB*KSEL)     // 23597872

// ws offsets (floats)
#define WS_ALOGIT 0
#define WS_ATTN   (NB*CC*NP)                 // 131072
#define WS_SELIDX (2*NB*CC*NP)               // 262144 (ints)
#define WS_MZ     (WS_SELIDX + NB*KSEL)      // 308016 (16 floats)
#define WS_BCNT   (WS_MZ + 16)               // ints (4)
#define WS_BLIST  (WS_BCNT + 4)              // ints (4*BCAP)
#define WS_TOP16  (WS_BLIST + NB*BCAP)       // ints (8*16)
#define WS_CE     (WS_TOP16 + 128)           // floats (128)

typedef __attribute__((ext_vector_type(8))) short short8x;
typedef __attribute__((ext_vector_type(4))) float f32x4;

__device__ __forceinline__ unsigned short f2bf(float x){
  unsigned u = __float_as_uint(x);
  unsigned r = (u + 0x7FFFu + ((u >> 16) & 1u)) >> 16;
  return (unsigned short)r;
}

// ---------------------------------------------------------------------------
// Wa (512x256 f32) -> Wa_t (256x512 bf16), transposed, stored at d_out head.
// ---------------------------------------------------------------------------
__global__ __launch_bounds__(256) void waconv_kernel(
    const float* __restrict__ Wa, unsigned short* __restrict__ WaT)
{
  __shared__ float tile[32][33];
  const int tx = threadIdx.x, ty = threadIdx.y;   // 32 x 8
  const int k0 = blockIdx.x * 32, n0 = blockIdx.y * 32;
  #pragma unroll
  for (int i=0;i<4;++i)
    tile[ty+8*i][tx] = Wa[(size_t)(k0+ty+8*i)*HH + n0 + tx];
  __syncthreads();
  #pragma unroll
  for (int i=0;i<4;++i)
    WaT[(size_t)(n0+ty+8*i)*DD + k0 + tx] = f2bf(tile[tx][ty+8*i]);
}

// ---------------------------------------------------------------------------
// MFMA GEMM: a_logits[b,c,n] = Wbr[c].relu(f[n]@Wa+ba) + bbr[c], bf16 inputs.
// BM=128, BN=256(full H), BK=64; 8 waves (2M x 4N), wave tile 64x64.
// (unchanged — proven)
// ---------------------------------------------------------------------------
__global__ __launch_bounds__(512) void gemm_mfma_kernel(
    const float* __restrict__ feat, const unsigned short* __restrict__ WaT,
    const float* __restrict__ ba, const float* __restrict__ Wbr,
    const float* __restrict__ bbr, float* __restrict__ aL)
{
  __shared__ __attribute__((aligned(16))) unsigned char smem[65536];
  __shared__ float sBA[HH], sW0[HH], sW1[HH];
  unsigned char* sA = smem;                 // 128*64 bf16 = 16 KB (swizzled)
  unsigned char* sB = smem + 16384;         // 256*64 bf16 = 32 KB (swizzled)

  const int tid  = threadIdx.x;
  const int lane = tid & 63;
  const int wid  = tid >> 6;
  const int wm = wid >> 2, wn = wid & 3;
  const int fr = lane & 15, fq = lane >> 4;
  const int p0 = blockIdx.x * 128;
  const float bb0 = bbr[0], bb1 = bbr[1];

  if (tid < HH){ sBA[tid] = ba[tid]; sW0[tid] = Wbr[tid]; sW1[tid] = Wbr[HH+tid]; }

  f32x4 acc[4][4];
  #pragma unroll
  for (int i=0;i<4;++i)
    #pragma unroll
    for (int j=0;j<4;++j)
      acc[i][j] = (f32x4){0.f,0.f,0.f,0.f};

  const int am = tid >> 2, akq = (tid & 3) * 16;     // A staging: row, k-offset
  const int bn = tid >> 1, bhf = tid & 1;            // B staging

  for (int k0 = 0; k0 < DD; k0 += 64){
    __syncthreads();
    // ---- stage A: 128x64 fp32 -> bf16, swizzled K-major
    {
      const float4* src = reinterpret_cast<const float4*>(
          feat + (size_t)(p0 + am)*DD + k0 + akq);
      float4 v0 = src[0], v1 = src[1], v2 = src[2], v3 = src[3];
      unsigned short u[16];
      u[0]=f2bf(v0.x); u[1]=f2bf(v0.y); u[2]=f2bf(v0.z); u[3]=f2bf(v0.w);
      u[4]=f2bf(v1.x); u[5]=f2bf(v1.y); u[6]=f2bf(v1.z); u[7]=f2bf(v1.w);
      u[8]=f2bf(v2.x); u[9]=f2bf(v2.y); u[10]=f2bf(v2.z); u[11]=f2bf(v2.w);
      u[12]=f2bf(v3.x); u[13]=f2bf(v3.y); u[14]=f2bf(v3.z); u[15]=f2bf(v3.w);
      uint4 w0, w1;
      w0.x = (unsigned)u[0] | ((unsigned)u[1]<<16);
      w0.y = (unsigned)u[2] | ((unsigned)u[3]<<16);
      w0.z = (unsigned)u[4] | ((unsigned)u[5]<<16);
      w0.w = (unsigned)u[6] | ((unsigned)u[7]<<16);
      w1.x = (unsigned)u[8] | ((unsigned)u[9]<<16);
      w1.y = (unsigned)u[10] | ((unsigned)u[11]<<16);
      w1.z = (unsigned)u[12] | ((unsigned)u[13]<<16);
      w1.w = (unsigned)u[14] | ((unsigned)u[15]<<16);
      const int swz = (am & 7) << 4;
      *reinterpret_cast<uint4*>(sA + (((am*128) + akq*2) ^ swz)) = w0;
      *reinterpret_cast<uint4*>(sA + (((am*128) + akq*2 + 16) ^ swz)) = w1;
    }
    // ---- stage B: 256x64 bf16 from WaT, swizzled K-major
    {
      const uint4* src = reinterpret_cast<const uint4*>(
          WaT + (size_t)bn*DD + k0 + bhf*32);
      uint4 q0 = src[0], q1 = src[1], q2 = src[2], q3 = src[3];
      const int swz = (bn & 7) << 4;
      const int base = bn*128 + bhf*64;
      *reinterpret_cast<uint4*>(sB + ((base     ) ^ swz)) = q0;
      *reinterpret_cast<uint4*>(sB + ((base + 16) ^ swz)) = q1;
      *reinterpret_cast<uint4*>(sB + ((base + 32) ^ swz)) = q2;
      *reinterpret_cast<uint4*>(sB + ((base + 48) ^ swz)) = q3;
    }
    __syncthreads();
    // ---- MFMA
    #pragma unroll
    for (int kf = 0; kf < 2; ++kf){
      short8x af[4], bf[4];
      #pragma unroll
      for (int mf = 0; mf < 4; ++mf){
        int m_loc = wm*64 + mf*16 + fr;
        int off = ((m_loc*128 + kf*64 + fq*16) ^ ((m_loc & 7) << 4));
        af[mf] = *reinterpret_cast<const short8x*>(sA + off);
      }
      #pragma unroll
      for (int nf = 0; nf < 4; ++nf){
        int n_loc = wn*64 + nf*16 + fr;
        int off = ((n_loc*128 + kf*64 + fq*16) ^ ((n_loc & 7) << 4));
        bf[nf] = *reinterpret_cast<const short8x*>(sB + off);
      }
      #pragma unroll
      for (int mf = 0; mf < 4; ++mf)
        #pragma unroll
        for (int nf = 0; nf < 4; ++nf)
          acc[mf][nf] = __builtin_amdgcn_mfma_f32_16x16x32_bf16(
              af[mf], bf[nf], acc[mf][nf], 0, 0, 0);
    }
  }
  __syncthreads();

  // ---- epilogue: relu + Wbr projection via LDS h-tile, M in halves of 64
  float* hS = reinterpret_cast<float*>(smem);
  #pragma unroll
  for (int mh = 0; mh < 2; ++mh){
    if (wm == mh){
      #pragma unroll
      for (int mf = 0; mf < 4; ++mf)
        #pragma unroll
        for (int nf = 0; nf < 4; ++nf)
          #pragma unroll
          for (int r = 0; r < 4; ++r){
            int row = mf*16 + fq*4 + r;
            int col = wn*64 + nf*16 + fr;
            hS[row*256 + col] = acc[mf][nf][r];
          }
    }
    __syncthreads();
    {
      const int row = tid >> 3, cg = tid & 7;
      float s0 = 0.f, s1 = 0.f;
      #pragma unroll
      for (int j = 0; j < 8; ++j){
        int col = cg*4 + j*32;
        float4 hv = *reinterpret_cast<const float4*>(&hS[row*256 + col]);
        float xs[4] = {hv.x, hv.y, hv.z, hv.w};
        #pragma unroll
        for (int u = 0; u < 4; ++u){
          int ccol = col + u;
          float x = fmaxf(xs[u] + sBA[ccol], 0.f);
          s0 += x * sW0[ccol];
          s1 += x * sW1[ccol];
        }
      }
      s0 += __shfl_xor(s0,1); s1 += __shfl_xor(s1,1);
      s0 += __shfl_xor(s0,2); s1 += __shfl_xor(s1,2);
      s0 += __shfl_xor(s0,4); s1 += __shfl_xor(s1,4);
      if (cg == 0){
        int p = p0 + mh*64 + row;
        int b = p >> 14, nl = p & (NP-1);
        aL[((size_t)b*CC + 0)*NP + nl] = s0 + bb0;
        aL[((size_t)b*CC + 1)*NP + nl] = s1 + bb1;
      }
    }
    __syncthreads();
  }
}

// ---------------------------------------------------------------------------
// Per-(b,c) row max + 1/Z (double accum). One block per row (8 blocks).
// Reduction order identical to previous softmax2 -> bit-identical m,iz.
// ---------------------------------------------------------------------------
__global__ __launch_bounds__(1024) void smstat_kernel(
    const float* __restrict__ aL, float* __restrict__ mz)
{
  __shared__ float  s_redf[16];
  __shared__ double s_redd[16];
  __shared__ float  s_max;
  const int tid = threadIdx.x;
  const int lane = tid & 63, wid = tid >> 6;
  const int r = blockIdx.x;                 // r = b*2 + c
  const float* a = aL + (size_t)r*NP;
  float m = -1e30f;
  for (int n=tid; n<NP; n+=1024) m = fmaxf(m, a[n]);
  #pragma unroll
  for (int off=1; off<64; off<<=1) m = fmaxf(m, __shfl_xor(m, off));
  if (lane==0) s_redf[wid]=m;
  __syncthreads();
  if (tid==0){ float mm=s_redf[0]; for(int w=1;w<16;++w) mm=fmaxf(mm,s_redf[w]); s_max=mm; }
  __syncthreads();
  m = s_max;
  double ls = 0.0;
  for (int n=tid;n<NP;n+=1024) ls += (double)expf(a[n]-m);
  #pragma unroll
  for (int off=1; off<64; off<<=1) ls += __shfl_xor(ls, off);
  if (lane==0) s_redd[wid]=ls;
  __syncthreads();
  if (tid==0){
    double t=0; for(int w=0;w<16;++w) t+=s_redd[w];
    mz[r*2+0]=m; mz[r*2+1]=(float)(1.0/t);
  }
}

// ---------------------------------------------------------------------------
// Fused: softmax finalize (attn, comb) + approximate threshold radix + band
// list. One block per batch. comb bits kept in LDS (no global round trip).
// ---------------------------------------------------------------------------
#define SKW 1028
__global__ __launch_bounds__(1024) void selTF_kernel(
    const float* __restrict__ aL, const float* __restrict__ mz,
    float* __restrict__ attn, float* __restrict__ comb,
    int* __restrict__ bcnt, int* __restrict__ blist)
{
  __shared__ unsigned s_bits[16*SKW];
  __shared__ unsigned s_red[16];
  __shared__ unsigned s_bcast;
  __shared__ int s_cnt;
  const int tid = threadIdx.x;
  const int b = blockIdx.x;
  const int lane = tid & 63, wid = tid >> 6;
  const float m0 = mz[b*4+0], iz0 = mz[b*4+1], m1 = mz[b*4+2], iz1 = mz[b*4+3];
  const float* a0 = aL + ((size_t)b*CC + 0)*NP;
  const float* a1 = aL + ((size_t)b*CC + 1)*NP;
  float* o0 = attn + ((size_t)b*CC + 0)*NP;
  float* o1 = attn + ((size_t)b*CC + 1)*NP;
  float* oc = comb + (size_t)b*NP;
  for (int j=0;j<16;++j){
    int n = tid + j*1024;
    float e0 = expf(a0[n]-m0)*iz0;
    float e1 = expf(a1[n]-m1)*iz1;
    o0[n]=e0; o1[n]=e1;
    float cv = 0.5f*(e0+e1);
    oc[n]=cv;
    s_bits[(n & 15)*SKW + (n >> 4)] = __float_as_uint(cv);
  }
  if (tid==0) s_cnt = 0;
  __syncthreads();
  unsigned cur = 0;
  for (int bit=31; bit>=12; --bit){
    unsigned trial = cur | (1u<<bit);
    int c = 0;
    #pragma unroll
    for (int j=0;j<16;++j) c += (s_bits[j*SKW + tid] >= trial) ? 1 : 0;
    #pragma unroll
    for (int off=1; off<64; off<<=1) c += __shfl_xor(c, off);
    if (lane==0) s_red[wid] = (unsigned)c;
    __syncthreads();
    if (tid==0){ unsigned t=0; for(int w=0;w<16;++w) t+=s_red[w]; s_bcast=t; }
    __syncthreads();
    if (s_bcast >= KSEL) cur = trial;
    __syncthreads();
  }
  const float Tv = __uint_as_float(cur);
  const float lo = Tv*0.989f, hi = Tv*1.0115f;
  #pragma unroll
  for (int e=0;e<16;++e){
    float v = __uint_as_float(s_bits[e*SKW + tid]);
    if (v >= lo && v <= hi){
      int s = atomicAdd(&s_cnt, 1);
      if (s < BCAP) blist[b*BCAP + s] = tid*16 + e;
    }
  }
  __syncthreads();
  if (tid==0) bcnt[b] = (s_cnt < BCAP) ? s_cnt : BCAP;
}

// ---------------------------------------------------------------------------
// Exact fp32 recompute of combined for band members.
// One block per candidate slot: grid = NB*BCAP, inactive blocks exit.
// ---------------------------------------------------------------------------
__global__ __launch_bounds__(256) void recomp_kernel(
    const float* __restrict__ feat, const float* __restrict__ Wa,
    const float* __restrict__ ba, const float* __restrict__ Wbr,
    const float* __restrict__ bbr, const float* __restrict__ mz,
    const int* __restrict__ bcnt, const int* __restrict__ blist,
    float* __restrict__ comb)
{
  __shared__ float fS[DD];
  __shared__ float r0[4], r1[4];
  const int tid = threadIdx.x;
  const int b = blockIdx.x >> 12;          // BCAP = 4096 slots per batch
  const int s = blockIdx.x & (BCAP-1);
  if (s >= bcnt[b]) return;
  const int lane = tid & 63, wid = tid >> 6;
  const float m0 = mz[b*4+0], iz0 = mz[b*4+1], m1 = mz[b*4+2], iz1 = mz[b*4+3];
  const int n = blist[b*BCAP + s];
  if (tid < 128){
    float4 v = *reinterpret_cast<const float4*>(feat + ((size_t)b*NP + n)*DD + tid*4);
    *reinterpret_cast<float4*>(&fS[tid*4]) = v;
  }
  __syncthreads();
  float a0=0.f,a1=0.f,a2=0.f,a3=0.f;
  #pragma unroll 4
  for (int d=0; d<DD; d+=4){
    a0 += fS[d+0]*Wa[(size_t)(d+0)*HH + tid];
    a1 += fS[d+1]*Wa[(size_t)(d+1)*HH + tid];
    a2 += fS[d+2]*Wa[(size_t)(d+2)*HH + tid];
    a3 += fS[d+3]*Wa[(size_t)(d+3)*HH + tid];
  }
  float h = fmaxf((a0+a1)+(a2+a3) + ba[tid], 0.f);
  float p0 = h*Wbr[tid], p1 = h*Wbr[HH+tid];
  #pragma unroll
  for (int off=1; off<64; off<<=1){ p0+=__shfl_xor(p0,off); p1+=__shfl_xor(p1,off); }
  if (lane==0){ r0[wid]=p0; r1[wid]=p1; }
  __syncthreads();
  if (tid==0){
    float l0 = (r0[0]+r0[1])+(r0[2]+r0[3]) + bbr[0];
    float l1 = (r1[0]+r1[1])+(r1[2]+r1[3]) + bbr[1];
    comb[(size_t)b*NP + n] = 0.5f*(expf(l0-m0)*iz0 + expf(l1-m1)*iz1);
  }
}

// ---------------------------------------------------------------------------
// Exact top-k selection on refined combined (proven kernel, unchanged).
// ---------------------------------------------------------------------------
__global__ __launch_bounds__(1024) void select_kernel(
    const float* __restrict__ comb, float* __restrict__ outIdxF,
    int* __restrict__ selIdx)
{
  __shared__ unsigned s_bits[16*SKW];
  __shared__ unsigned s_red[16];
  __shared__ unsigned s_scan[1024];
  __shared__ unsigned s_bcast;
  const int tid = threadIdx.x;
  const int b = blockIdx.x;
  const int lane = tid & 63, wid = tid >> 6;
  const float* row = comb + (size_t)b*NP;
  for (int j=0;j<16;++j){
    int n = tid + j*1024;
    s_bits[(n & 15)*SKW + (n >> 4)] = __float_as_uint(row[n]);
  }
  __syncthreads();
  unsigned cur = 0;
  for (int bit=31; bit>=0; --bit){
    unsigned trial = cur | (1u<<bit);
    int c = 0;
    #pragma unroll
    for (int j=0;j<16;++j) c += (s_bits[j*SKW + tid] >= trial) ? 1 : 0;
    #pragma unroll
    for (int off=1; off<64; off<<=1) c += __shfl_xor(c, off);
    if (lane==0) s_red[wid] = (unsigned)c;
    __syncthreads();
    if (tid==0){ unsigned t=0; for(int w=0;w<16;++w) t+=s_red[w]; s_bcast=t; }
    __syncthreads();
    if (s_bcast >= KSEL) cur = trial;
    __syncthreads();
  }
  const unsigned T = cur;
  {
    int c = 0;
    #pragma unroll
    for (int j=0;j<16;++j) c += (s_bits[j*SKW + tid] > T) ? 1 : 0;
    #pragma unroll
    for (int off=1; off<64; off<<=1) c += __shfl_xor(c, off);
    if (lane==0) s_red[wid] = (unsigned)c;
    __syncthreads();
    if (tid==0){ unsigned t=0; for(int w=0;w<16;++w) t+=s_red[w]; s_bcast=t; }
    __syncthreads();
  }
  const int extra = KSEL - (int)s_bcast;
  __syncthreads();
  int eqc=0;
  #pragma unroll
  for (int e=0;e<16;++e) eqc += (s_bits[e*SKW + tid]==T) ? 1 : 0;
  s_scan[tid]=(unsigned)eqc;
  __syncthreads();
  for (int off=1; off<1024; off<<=1){
    unsigned v = (tid>=off)? s_scan[tid-off] : 0u;
    __syncthreads();
    s_scan[tid]+=v;
    __syncthreads();
  }
  const int eqBase = (int)s_scan[tid] - eqc;
  __syncthreads();
  int eq=eqBase, sc=0;
  #pragma unroll
  for (int e=0;e<16;++e){
    unsigned v = s_bits[e*SKW + tid];
    if (v==T){ if (eq<extra) sc++; eq++; }
    else if (v>T) sc++;
  }
  s_scan[tid]=(unsigned)sc;
  __syncthreads();
  for (int off=1; off<1024; off<<=1){
    unsigned v = (tid>=off)? s_scan[tid-off] : 0u;
    __syncthreads();
    s_scan[tid]+=v;
    __syncthreads();
  }
  int pos = (int)s_scan[tid] - sc;
  eq=eqBase;
  #pragma unroll
  for (int e=0;e<16;++e){
    unsigned v = s_bits[e*SKW + tid];
    int f=0;
    if (v==T){ if (eq<extra) f=1; eq++; }
    else if (v>T) f=1;
    if (f){
      int n = tid*16 + e;
      outIdxF[(size_t)b*KSEL + pos] = (float)n;
      selIdx[(size_t)b*KSEL + pos] = n;
      pos++;
    }
  }
}

// ---------------------------------------------------------------------------
// Gather selected rows.
// ---------------------------------------------------------------------------
__global__ __launch_bounds__(256) void gather_kernel(
    const float* __restrict__ feat, const int* __restrict__ selIdx,
    float* __restrict__ outSel)
{
  const int tid = threadIdx.x;
  const int row = blockIdx.x*2 + (tid>>7);
  const int c4 = tid & 127;
  const int b = row / KSEL;
  const int idx = selIdx[row];
  const float4 v = *reinterpret_cast<const float4*>(feat + ((size_t)b*NP + idx)*DD + c4*4);
  *reinterpret_cast<float4*>(outSel + (size_t)row*DD + c4*4) = v;
}

// ---------------------------------------------------------------------------
// Per-(b,c) top-8/bottom-8, lax.top_k tie semantics. Wave-parallel picks:
// per-thread top8/bot8 (one float4 pass), per-wave shuffle pick-8 (no
// barriers), single cross-wave merge by wave 0. Keys unique (index embedded).
// ---------------------------------------------------------------------------
__global__ __launch_bounds__(256) void top16_kernel(
    const float* __restrict__ attn, int* __restrict__ top16)
{
  __shared__ unsigned long long wkT[4][8];
  __shared__ unsigned long long wkB[4][8];
  const int tid = threadIdx.x;
  const int bid = blockIdx.x;
  const int lane = tid & 63, wid = tid >> 6;
  const float* a = attn + (size_t)bid*NP;

  unsigned long long t8[8], b8[8];
  #pragma unroll
  for (int i=0;i<8;++i){ t8[i]=0ull; b8[i]=~0ull; }

  for (int j=0;j<16;++j){
    const int n4 = tid + 256*j;
    const float4 v = *reinterpret_cast<const float4*>(a + 4*n4);
    const float xs[4] = {v.x, v.y, v.z, v.w};
    #pragma unroll
    for (int q=0;q<4;++q){
      const int n = 4*n4 + q;
      const unsigned vb = __float_as_uint(xs[q]);
      unsigned long long kt = ((unsigned long long)vb<<32) | (unsigned)(NP-1-n);
      if (kt > t8[7]){
        t8[7]=kt;
        #pragma unroll
        for (int i=7;i>0;--i){ if (t8[i]>t8[i-1]){ unsigned long long t=t8[i-1]; t8[i-1]=t8[i]; t8[i]=t; } }
      }
      unsigned long long kb = ((unsigned long long)vb<<32) | (unsigned)n;
      if (kb < b8[7]){
        b8[7]=kb;
        #pragma unroll
        for (int i=7;i>0;--i){ if (b8[i]<b8[i-1]){ unsigned long long t=b8[i-1]; b8[i-1]=b8[i]; b8[i]=t; } }
      }
    }
  }

  // per-wave top-8 (no barriers)
  #pragma unroll
  for (int pick=0; pick<8; ++pick){
    unsigned long long loc = t8[0];
    #pragma unroll
    for (int i=1;i<8;++i) loc = t8[i]>loc ? t8[i] : loc;
    #pragma unroll
    for (int off=1; off<64; off<<=1){ unsigned long long o=__shfl_xor(loc,off); loc=o>loc?o:loc; }
    if (lane==0) wkT[wid][pick]=loc;
    #pragma unroll
    for (int i=0;i<8;++i) if (t8[i]==loc) t8[i]=0ull;
  }
  // per-wave bottom-8
  #pragma unroll
  for (int pick=0; pick<8; ++pick){
    unsigned long long loc = b8[0];
    #pragma unroll
    for (int i=1;i<8;++i) loc = b8[i]<loc ? b8[i] : loc;
    #pragma unroll
    for (int off=1; off<64; off<<=1){ unsigned long long o=__shfl_xor(loc,off); loc=o<loc?o:loc; }
    if (lane==0) wkB[wid][pick]=loc;
    #pragma unroll
    for (int i=0;i<8;++i) if (b8[i]==loc) b8[i]=~0ull;
  }
  __syncthreads();

  if (wid==0){
    // merge 4x8 top keys
    unsigned long long k = (lane<32) ? wkT[lane>>3][lane&7] : 0ull;
    #pragma unroll
    for (int pick=0; pick<8; ++pick){
      unsigned long long loc = k;
      #pragma unroll
      for (int off=1; off<64; off<<=1){ unsigned long long o=__shfl_xor(loc,off); loc=o>loc?o:loc; }
      if (k==loc) k=0ull;
      if (lane==0) top16[bid*16+pick] = NP-1-(int)(loc & 0xFFFFFFFFull);
    }
    // merge 4x8 bottom keys
    unsigned long long kb = (lane<32) ? wkB[lane>>3][lane&7] : ~0ull;
    #pragma unroll
    for (int pick=0; pick<8; ++pick){
      unsigned long long loc = kb;
      #pragma unroll
      for (int off=1; off<64; off<<=1){ unsigned long long o=__shfl_xor(loc,off); loc=o<loc?o:loc; }
      if (kb==loc) kb=~0ull;
      if (lane==0) top16[bid*16+8+pick] = (int)(loc & 0xFFFFFFFFull);
    }
  }
}

// ---------------------------------------------------------------------------
// Instance MLP + CE partial, one block per (b,c,r).
// ---------------------------------------------------------------------------
__global__ __launch_bounds__(256) void mlp_kernel(
    const float* __restrict__ feat, const float* __restrict__ W1,
    const float* __restrict__ b1, const float* __restrict__ W2,
    const float* __restrict__ b2, const int* __restrict__ top16,
    float* __restrict__ cews)
{
  __shared__ float fS[DD];
  __shared__ float r0[4], r1[4];
  const int tid = threadIdx.x;
  const int bid = blockIdx.x;
  const int r = bid & 15, c = (bid >> 4) & 1, b = bid >> 5;
  const int lane = tid & 63, wid = tid >> 6;
  const int gi = top16[(b*2+c)*16 + r];
  if (tid < 128){
    float4 v = *reinterpret_cast<const float4*>(feat + ((size_t)b*NP + gi)*DD + tid*4);
    *reinterpret_cast<float4*>(&fS[tid*4]) = v;
  }
  __syncthreads();
  const float* w1c = W1 + (size_t)c*DD*HH;
  float a0=0.f,a1=0.f,a2=0.f,a3=0.f;
  #pragma unroll 4
  for (int d=0; d<DD; d+=4){
    a0 += fS[d+0]*w1c[(size_t)(d+0)*HH + tid];
    a1 += fS[d+1]*w1c[(size_t)(d+1)*HH + tid];
    a2 += fS[d+2]*w1c[(size_t)(d+2)*HH + tid];
    a3 += fS[d+3]*w1c[(size_t)(d+3)*HH + tid];
  }
  float h = fmaxf((a0+a1)+(a2+a3) + b1[c*HH+tid], 0.f);
  float p0 = h*W2[(size_t)(c*HH+tid)*2 + 0];
  float p1 = h*W2[(size_t)(c*HH+tid)*2 + 1];
  #pragma unroll
  for (int off=1; off<64; off<<=1){ p0+=__shfl_xor(p0,off); p1+=__shfl_xor(p1,off); }
  if (lane==0){ r0[wid]=p0; r1[wid]=p1; }
  __syncthreads();
  if (tid==0){
    float l0 = (r0[0]+r0[1])+(r0[2]+r0[3]) + b2[c*2+0];
    float l1 = (r1[0]+r1[1])+(r1[2]+r1[3]) + b2[c*2+1];
    float mm = fmaxf(l0,l1);
    float lse = mm + logf(expf(l0-mm)+expf(l1-mm));
    float chosen = (r<8) ? l1 : l0;
    cews[bid] = lse - chosen;
  }
}

__global__ void loss_kernel(const float* __restrict__ cews, float* __restrict__ out_loss){
  if (threadIdx.x==0 && blockIdx.x==0){
    float s=0.f;
    for (int i=0;i<128;++i) s += cews[i];
    out_loss[0] = s / 128.0f;
  }
}

extern "C" void kernel_launch(void* const* d_in, const int* in_sizes, int n_in,
                              void* d_out, int out_size, void* d_ws, size_t ws_size,
                              hipStream_t stream) {
  const float* feat = (const float*)d_in[0];
  const float* Wa   = (const float*)d_in[1];
  const float* ba   = (const float*)d_in[2];
  const float* Wbr  = (const float*)d_in[3];
  const float* bbr  = (const float*)d_in[4];
  const float* W1   = (const float*)d_in[5];
  const float* b1   = (const float*)d_in[6];
  const float* W2   = (const float*)d_in[7];
  const float* b2   = (const float*)d_in[8];
  float* out = (float*)d_out;
  float* ws  = (float*)d_ws;

  float* a_logits = ws + WS_ALOGIT;
  float* attn     = ws + WS_ATTN;
  int*   selIdx   = (int*)(ws + WS_SELIDX);
  float* mz       = ws + WS_MZ;
  int*   bcnt     = (int*)(ws + WS_BCNT);
  int*   blist    = (int*)(ws + WS_BLIST);
  int*   top16    = (int*)(ws + WS_TOP16);
  float* cews     = ws + WS_CE;

  unsigned short* WaT = (unsigned short*)d_out;   // head of selected region;
                                                  // fully overwritten by gather

  hipLaunchKernelGGL(waconv_kernel, dim3(DD/32, HH/32), dim3(32,8), 0, stream,
                     Wa, WaT);
  hipLaunchKernelGGL(gemm_mfma_kernel, dim3(TOTP/128), dim3(512), 0, stream,
                     feat, WaT, ba, Wbr, bbr, a_logits);
  hipLaunchKernelGGL(smstat_kernel, dim3(NB*CC), dim3(1024), 0, stream,
                     a_logits, mz);
  hipLaunchKernelGGL(selTF_kernel, dim3(NB), dim3(1024), 0, stream,
                     a_logits, mz, attn, out + OFF_COMB, bcnt, blist);
  hipLaunchKernelGGL(recomp_kernel, dim3(NB*BCAP), dim3(256), 0, stream,
                     feat, Wa, ba, Wbr, bbr, mz, bcnt, blist, out + OFF_COMB);
  hipLaunchKernelGGL(select_kernel, dim3(NB), dim3(1024), 0, stream,
                     out + OFF_COMB, out + OFF_IDX, selIdx);
  hipLaunchKernelGGL(gather_kernel, dim3(NB*KSEL/2), dim3(256), 0, stream,
                     feat, selIdx, out);
  hipLaunchKernelGGL(top16_kernel, dim3(NB*CC), dim3(256), 0, stream,
                     attn, top16);
  hipLaunchKernelGGL(mlp_kernel, dim3(NB*CC*16), dim3(256), 0, stream,
                     feat, W1, b1, W2, b2, top16, cews);
  hipLaunchKernelGGL(loss_kernel, dim3(1), dim3(64), 0, stream,
                     cews, out + OFF_LOSS);
}

// Round 5
// 275.327 us; speedup vs baseline: 1.7200x; 1.0306x over previous
//
#include <hip/hip_runtime.h>

#define NB 4
#define NP 16384
#define DD 512
#define HH 256
#define CC 2
#define KSEL 11468
#define TOTP (NB*NP)
#define BCAP 4096

// d_out offsets (floats)
#define OFF_COMB (NB*KSEL*DD)            // 23486464
#define OFF_IDX  (OFF_COMB + NB*NP)      // 23552000
#define OFF_LOSS (OFF_IDX + NB*KSEL)     // 23597872

// ws offsets (floats)
#define WS_ALOGIT 0
#define WS_ATTN   (NB*CC*NP)                 // 131072
#define WS_SELIDX (2*NB*CC*NP)               // 262144 (ints)
#define WS_MZ     (WS_SELIDX + NB*KSEL)      // 308016 (16 floats)
#define WS_BCNT   (WS_MZ + 16)               // ints (4)
#define WS_BLIST  (WS_BCNT + 4)              // ints (4*BCAP)
#define WS_TOP16  (WS_BLIST + NB*BCAP)       // ints (8*16)
#define WS_CE     (WS_TOP16 + 128)           // floats (128)

typedef __attribute__((ext_vector_type(8))) short short8x;
typedef __attribute__((ext_vector_type(4))) float f32x4;

__device__ __forceinline__ unsigned short f2bf(float x){
  unsigned u = __float_as_uint(x);
  unsigned r = (u + 0x7FFFu + ((u >> 16) & 1u)) >> 16;
  return (unsigned short)r;
}

// ---------------------------------------------------------------------------
// Wa (512x256 f32) -> Wa_t (256x512 bf16), transposed, stored at d_out head.
// ---------------------------------------------------------------------------
__global__ __launch_bounds__(256) void waconv_kernel(
    const float* __restrict__ Wa, unsigned short* __restrict__ WaT)
{
  __shared__ float tile[32][33];
  const int tx = threadIdx.x, ty = threadIdx.y;   // 32 x 8
  const int k0 = blockIdx.x * 32, n0 = blockIdx.y * 32;
  #pragma unroll
  for (int i=0;i<4;++i)
    tile[ty+8*i][tx] = Wa[(size_t)(k0+ty+8*i)*HH + n0 + tx];
  __syncthreads();
  #pragma unroll
  for (int i=0;i<4;++i)
    WaT[(size_t)(n0+ty+8*i)*DD + k0 + tx] = f2bf(tile[tx][ty+8*i]);
}

// ---------------------------------------------------------------------------
// MFMA GEMM: a_logits[b,c,n] = Wbr[c].relu(f[n]@Wa+ba) + bbr[c], bf16 inputs.
// BM=128, BN=256(full H), BK=64; 8 waves (2M x 4N), wave tile 64x64.
// (unchanged — proven)
// ---------------------------------------------------------------------------
__global__ __launch_bounds__(512) void gemm_mfma_kernel(
    const float* __restrict__ feat, const unsigned short* __restrict__ WaT,
    const float* __restrict__ ba, const float* __restrict__ Wbr,
    const float* __restrict__ bbr, float* __restrict__ aL)
{
  __shared__ __attribute__((aligned(16))) unsigned char smem[65536];
  __shared__ float sBA[HH], sW0[HH], sW1[HH];
  unsigned char* sA = smem;                 // 128*64 bf16 = 16 KB (swizzled)
  unsigned char* sB = smem + 16384;         // 256*64 bf16 = 32 KB (swizzled)

  const int tid  = threadIdx.x;
  const int lane = tid & 63;
  const int wid  = tid >> 6;
  const int wm = wid >> 2, wn = wid & 3;
  const int fr = lane & 15, fq = lane >> 4;
  const int p0 = blockIdx.x * 128;
  const float bb0 = bbr[0], bb1 = bbr[1];

  if (tid < HH){ sBA[tid] = ba[tid]; sW0[tid] = Wbr[tid]; sW1[tid] = Wbr[HH+tid]; }

  f32x4 acc[4][4];
  #pragma unroll
  for (int i=0;i<4;++i)
    #pragma unroll
    for (int j=0;j<4;++j)
      acc[i][j] = (f32x4){0.f,0.f,0.f,0.f};

  const int am = tid >> 2, akq = (tid & 3) * 16;     // A staging: row, k-offset
  const int bn = tid >> 1, bhf = tid & 1;            // B staging

  for (int k0 = 0; k0 < DD; k0 += 64){
    __syncthreads();
    // ---- stage A: 128x64 fp32 -> bf16, swizzled K-major
    {
      const float4* src = reinterpret_cast<const float4*>(
          feat + (size_t)(p0 + am)*DD + k0 + akq);
      float4 v0 = src[0], v1 = src[1], v2 = src[2], v3 = src[3];
      unsigned short u[16];
      u[0]=f2bf(v0.x); u[1]=f2bf(v0.y); u[2]=f2bf(v0.z); u[3]=f2bf(v0.w);
      u[4]=f2bf(v1.x); u[5]=f2bf(v1.y); u[6]=f2bf(v1.z); u[7]=f2bf(v1.w);
      u[8]=f2bf(v2.x); u[9]=f2bf(v2.y); u[10]=f2bf(v2.z); u[11]=f2bf(v2.w);
      u[12]=f2bf(v3.x); u[13]=f2bf(v3.y); u[14]=f2bf(v3.z); u[15]=f2bf(v3.w);
      uint4 w0, w1;
      w0.x = (unsigned)u[0] | ((unsigned)u[1]<<16);
      w0.y = (unsigned)u[2] | ((unsigned)u[3]<<16);
      w0.z = (unsigned)u[4] | ((unsigned)u[5]<<16);
      w0.w = (unsigned)u[6] | ((unsigned)u[7]<<16);
      w1.x = (unsigned)u[8] | ((unsigned)u[9]<<16);
      w1.y = (unsigned)u[10] | ((unsigned)u[11]<<16);
      w1.z = (unsigned)u[12] | ((unsigned)u[13]<<16);
      w1.w = (unsigned)u[14] | ((unsigned)u[15]<<16);
      const int swz = (am & 7) << 4;
      *reinterpret_cast<uint4*>(sA + (((am*128) + akq*2) ^ swz)) = w0;
      *reinterpret_cast<uint4*>(sA + (((am*128) + akq*2 + 16) ^ swz)) = w1;
    }
    // ---- stage B: 256x64 bf16 from WaT, swizzled K-major
    {
      const uint4* src = reinterpret_cast<const uint4*>(
          WaT + (size_t)bn*DD + k0 + bhf*32);
      uint4 q0 = src[0], q1 = src[1], q2 = src[2], q3 = src[3];
      const int swz = (bn & 7) << 4;
      const int base = bn*128 + bhf*64;
      *reinterpret_cast<uint4*>(sB + ((base     ) ^ swz)) = q0;
      *reinterpret_cast<uint4*>(sB + ((base + 16) ^ swz)) = q1;
      *reinterpret_cast<uint4*>(sB + ((base + 32) ^ swz)) = q2;
      *reinterpret_cast<uint4*>(sB + ((base + 48) ^ swz)) = q3;
    }
    __syncthreads();
    // ---- MFMA
    #pragma unroll
    for (int kf = 0; kf < 2; ++kf){
      short8x af[4], bf[4];
      #pragma unroll
      for (int mf = 0; mf < 4; ++mf){
        int m_loc = wm*64 + mf*16 + fr;
        int off = ((m_loc*128 + kf*64 + fq*16) ^ ((m_loc & 7) << 4));
        af[mf] = *reinterpret_cast<const short8x*>(sA + off);
      }
      #pragma unroll
      for (int nf = 0; nf < 4; ++nf){
        int n_loc = wn*64 + nf*16 + fr;
        int off = ((n_loc*128 + kf*64 + fq*16) ^ ((n_loc & 7) << 4));
        bf[nf] = *reinterpret_cast<const short8x*>(sB + off);
      }
      #pragma unroll
      for (int mf = 0; mf < 4; ++mf)
        #pragma unroll
        for (int nf = 0; nf < 4; ++nf)
          acc[mf][nf] = __builtin_amdgcn_mfma_f32_16x16x32_bf16(
              af[mf], bf[nf], acc[mf][nf], 0, 0, 0);
    }
  }
  __syncthreads();

  // ---- epilogue: relu + Wbr projection via LDS h-tile, M in halves of 64
  float* hS = reinterpret_cast<float*>(smem);
  #pragma unroll
  for (int mh = 0; mh < 2; ++mh){
    if (wm == mh){
      #pragma unroll
      for (int mf = 0; mf < 4; ++mf)
        #pragma unroll
        for (int nf = 0; nf < 4; ++nf)
          #pragma unroll
          for (int r = 0; r < 4; ++r){
            int row = mf*16 + fq*4 + r;
            int col = wn*64 + nf*16 + fr;
            hS[row*256 + col] = acc[mf][nf][r];
          }
    }
    __syncthreads();
    {
      const int row = tid >> 3, cg = tid & 7;
      float s0 = 0.f, s1 = 0.f;
      #pragma unroll
      for (int j = 0; j < 8; ++j){
        int col = cg*4 + j*32;
        float4 hv = *reinterpret_cast<const float4*>(&hS[row*256 + col]);
        float xs[4] = {hv.x, hv.y, hv.z, hv.w};
        #pragma unroll
        for (int u = 0; u < 4; ++u){
          int ccol = col + u;
          float x = fmaxf(xs[u] + sBA[ccol], 0.f);
          s0 += x * sW0[ccol];
          s1 += x * sW1[ccol];
        }
      }
      s0 += __shfl_xor(s0,1); s1 += __shfl_xor(s1,1);
      s0 += __shfl_xor(s0,2); s1 += __shfl_xor(s1,2);
      s0 += __shfl_xor(s0,4); s1 += __shfl_xor(s1,4);
      if (cg == 0){
        int p = p0 + mh*64 + row;
        int b = p >> 14, nl = p & (NP-1);
        aL[((size_t)b*CC + 0)*NP + nl] = s0 + bb0;
        aL[((size_t)b*CC + 1)*NP + nl] = s1 + bb1;
      }
    }
    __syncthreads();
  }
}

// ---------------------------------------------------------------------------
// Per-(b,c) row max + 1/Z (double accum). One block per row (8 blocks).
// (unchanged — proven)
// ---------------------------------------------------------------------------
__global__ __launch_bounds__(1024) void smstat_kernel(
    const float* __restrict__ aL, float* __restrict__ mz)
{
  __shared__ float  s_redf[16];
  __shared__ double s_redd[16];
  __shared__ float  s_max;
  const int tid = threadIdx.x;
  const int lane = tid & 63, wid = tid >> 6;
  const int r = blockIdx.x;                 // r = b*2 + c
  const float* a = aL + (size_t)r*NP;
  float m = -1e30f;
  for (int n=tid; n<NP; n+=1024) m = fmaxf(m, a[n]);
  #pragma unroll
  for (int off=1; off<64; off<<=1) m = fmaxf(m, __shfl_xor(m, off));
  if (lane==0) s_redf[wid]=m;
  __syncthreads();
  if (tid==0){ float mm=s_redf[0]; for(int w=1;w<16;++w) mm=fmaxf(mm,s_redf[w]); s_max=mm; }
  __syncthreads();
  m = s_max;
  double ls = 0.0;
  for (int n=tid;n<NP;n+=1024) ls += (double)expf(a[n]-m);
  #pragma unroll
  for (int off=1; off<64; off<<=1) ls += __shfl_xor(ls, off);
  if (lane==0) s_redd[wid]=ls;
  __syncthreads();
  if (tid==0){
    double t=0; for(int w=0;w<16;++w) t+=s_redd[w];
    mz[r*2+0]=m; mz[r*2+1]=(float)(1.0/t);
  }
}

// ---------------------------------------------------------------------------
// Fused: softmax finalize (attn, comb) + approx threshold radix + band list.
// Register-resident: each thread owns chunk n = tid*16..tid*16+15 in VGPRs.
// 1 barrier per radix round (double-buffered s_red).
// ---------------------------------------------------------------------------
__global__ __launch_bounds__(1024) void selTF_kernel(
    const float* __restrict__ aL, const float* __restrict__ mz,
    float* __restrict__ attn, float* __restrict__ comb,
    int* __restrict__ bcnt, int* __restrict__ blist)
{
  __shared__ unsigned s_red[2][16];
  __shared__ int s_cnt;
  const int tid = threadIdx.x;
  const int b = blockIdx.x;
  const int lane = tid & 63, wid = tid >> 6;
  const float m0 = mz[b*4+0], iz0 = mz[b*4+1], m1 = mz[b*4+2], iz1 = mz[b*4+3];
  const float* a0 = aL + ((size_t)b*CC + 0)*NP;
  const float* a1 = aL + ((size_t)b*CC + 1)*NP;
  float* o0 = attn + ((size_t)b*CC + 0)*NP;
  float* o1 = attn + ((size_t)b*CC + 1)*NP;
  float* oc = comb + (size_t)b*NP;
  const int n0 = tid*16;

  unsigned v[16];
  #pragma unroll
  for (int g=0; g<4; ++g){
    float4 qa = *reinterpret_cast<const float4*>(a0 + n0 + g*4);
    float4 qb = *reinterpret_cast<const float4*>(a1 + n0 + g*4);
    float4 E0, E1, CV;
    E0.x = expf(qa.x-m0)*iz0; E1.x = expf(qb.x-m1)*iz1; CV.x = 0.5f*(E0.x+E1.x);
    E0.y = expf(qa.y-m0)*iz0; E1.y = expf(qb.y-m1)*iz1; CV.y = 0.5f*(E0.y+E1.y);
    E0.z = expf(qa.z-m0)*iz0; E1.z = expf(qb.z-m1)*iz1; CV.z = 0.5f*(E0.z+E1.z);
    E0.w = expf(qa.w-m0)*iz0; E1.w = expf(qb.w-m1)*iz1; CV.w = 0.5f*(E0.w+E1.w);
    *reinterpret_cast<float4*>(o0 + n0 + g*4) = E0;
    *reinterpret_cast<float4*>(o1 + n0 + g*4) = E1;
    *reinterpret_cast<float4*>(oc + n0 + g*4) = CV;
    v[g*4+0]=__float_as_uint(CV.x);
    v[g*4+1]=__float_as_uint(CV.y);
    v[g*4+2]=__float_as_uint(CV.z);
    v[g*4+3]=__float_as_uint(CV.w);
  }
  if (tid==0) s_cnt = 0;

  unsigned cur = 0;
  #pragma unroll 1
  for (int bit=31; bit>=12; --bit){
    unsigned trial = cur | (1u<<bit);
    int c = 0;
    #pragma unroll
    for (int i=0;i<16;++i) c += (v[i] >= trial) ? 1 : 0;
    #pragma unroll
    for (int off=1; off<64; off<<=1) c += __shfl_xor(c, off);
    if (lane==0) s_red[bit&1][wid] = (unsigned)c;
    __syncthreads();
    unsigned tot=0;
    #pragma unroll
    for (int w=0;w<16;++w) tot += s_red[bit&1][w];
    if (tot >= KSEL) cur = trial;
  }
  const float Tv = __uint_as_float(cur);
  const float lo = Tv*0.989f, hi = Tv*1.0115f;
  #pragma unroll
  for (int i=0;i<16;++i){
    float x = __uint_as_float(v[i]);
    if (x >= lo && x <= hi){
      int s = atomicAdd(&s_cnt, 1);
      if (s < BCAP) blist[b*BCAP + s] = n0 + i;
    }
  }
  __syncthreads();
  if (tid==0) bcnt[b] = (s_cnt < BCAP) ? s_cnt : BCAP;
}

// ---------------------------------------------------------------------------
// Exact fp32 recompute of combined for band members.
// One block per candidate slot: grid = NB*BCAP, inactive blocks exit.
// (unchanged — proven)
// ---------------------------------------------------------------------------
__global__ __launch_bounds__(256) void recomp_kernel(
    const float* __restrict__ feat, const float* __restrict__ Wa,
    const float* __restrict__ ba, const float* __restrict__ Wbr,
    const float* __restrict__ bbr, const float* __restrict__ mz,
    const int* __restrict__ bcnt, const int* __restrict__ blist,
    float* __restrict__ comb)
{
  __shared__ float fS[DD];
  __shared__ float r0[4], r1[4];
  const int tid = threadIdx.x;
  const int b = blockIdx.x >> 12;          // BCAP = 4096 slots per batch
  const int s = blockIdx.x & (BCAP-1);
  if (s >= bcnt[b]) return;
  const int lane = tid & 63, wid = tid >> 6;
  const float m0 = mz[b*4+0], iz0 = mz[b*4+1], m1 = mz[b*4+2], iz1 = mz[b*4+3];
  const int n = blist[b*BCAP + s];
  if (tid < 128){
    float4 v = *reinterpret_cast<const float4*>(feat + ((size_t)b*NP + n)*DD + tid*4);
    *reinterpret_cast<float4*>(&fS[tid*4]) = v;
  }
  __syncthreads();
  float a0=0.f,a1=0.f,a2=0.f,a3=0.f;
  #pragma unroll 4
  for (int d=0; d<DD; d+=4){
    a0 += fS[d+0]*Wa[(size_t)(d+0)*HH + tid];
    a1 += fS[d+1]*Wa[(size_t)(d+1)*HH + tid];
    a2 += fS[d+2]*Wa[(size_t)(d+2)*HH + tid];
    a3 += fS[d+3]*Wa[(size_t)(d+3)*HH + tid];
  }
  float h = fmaxf((a0+a1)+(a2+a3) + ba[tid], 0.f);
  float p0 = h*Wbr[tid], p1 = h*Wbr[HH+tid];
  #pragma unroll
  for (int off=1; off<64; off<<=1){ p0+=__shfl_xor(p0,off); p1+=__shfl_xor(p1,off); }
  if (lane==0){ r0[wid]=p0; r1[wid]=p1; }
  __syncthreads();
  if (tid==0){
    float l0 = (r0[0]+r0[1])+(r0[2]+r0[3]) + bbr[0];
    float l1 = (r1[0]+r1[1])+(r1[2]+r1[3]) + bbr[1];
    comb[(size_t)b*NP + n] = 0.5f*(expf(l0-m0)*iz0 + expf(l1-m1)*iz1);
  }
}

// ---------------------------------------------------------------------------
// Exact top-k selection on refined combined. Register-resident chunks:
// thread tid owns n = tid*16..tid*16+15 (same ownership as emission), so
// sel_idx output is byte-identical to the proven LDS version.
// ---------------------------------------------------------------------------
__global__ __launch_bounds__(1024) void select_kernel(
    const float* __restrict__ comb, float* __restrict__ outIdxF,
    int* __restrict__ selIdx)
{
  __shared__ unsigned s_red[2][16];
  __shared__ unsigned s_wsum[16];
  const int tid = threadIdx.x;
  const int b = blockIdx.x;
  const int lane = tid & 63, wid = tid >> 6;
  const float* row = comb + (size_t)b*NP;

  unsigned v[16];
  {
    const float4* rp = reinterpret_cast<const float4*>(row + tid*16);
    #pragma unroll
    for (int g=0; g<4; ++g){
      float4 q = rp[g];
      v[g*4+0]=__float_as_uint(q.x);
      v[g*4+1]=__float_as_uint(q.y);
      v[g*4+2]=__float_as_uint(q.z);
      v[g*4+3]=__float_as_uint(q.w);
    }
  }
  // ---- radix threshold (32 rounds, 1 barrier each)
  unsigned cur = 0;
  #pragma unroll 1
  for (int bit=31; bit>=0; --bit){
    unsigned trial = cur | (1u<<bit);
    int c = 0;
    #pragma unroll
    for (int i=0;i<16;++i) c += (v[i] >= trial) ? 1 : 0;
    #pragma unroll
    for (int off=1; off<64; off<<=1) c += __shfl_xor(c, off);
    if (lane==0) s_red[bit&1][wid] = (unsigned)c;
    __syncthreads();
    unsigned tot=0;
    #pragma unroll
    for (int w=0;w<16;++w) tot += s_red[bit&1][w];
    if (tot >= KSEL) cur = trial;
  }
  const unsigned T = cur;
  // ---- strictly-greater count (use buffer 1: safe per barrier ordering)
  {
    int c = 0;
    #pragma unroll
    for (int i=0;i<16;++i) c += (v[i] > T) ? 1 : 0;
    #pragma unroll
    for (int off=1; off<64; off<<=1) c += __shfl_xor(c, off);
    if (lane==0) s_red[1][wid] = (unsigned)c;
  }
  __syncthreads();
  unsigned gtot=0;
  #pragma unroll
  for (int w=0;w<16;++w) gtot += s_red[1][w];
  const int extra = KSEL - (int)gtot;

  // ---- exclusive prefix of equality counts (wave scan + cross-wave base)
  int eqc=0;
  #pragma unroll
  for (int i=0;i<16;++i) eqc += (v[i]==T) ? 1 : 0;
  unsigned inc = (unsigned)eqc;
  #pragma unroll
  for (int off=1; off<64; off<<=1){
    unsigned o = __shfl_up(inc, off);
    if (lane >= off) inc += o;
  }
  if (lane==63) s_wsum[wid] = inc;
  __syncthreads();
  unsigned wbase = 0;
  for (int w=0; w<wid; ++w) wbase += s_wsum[w];
  const int eqBase = (int)(wbase + inc) - eqc;

  // ---- selected-count prefix
  int eq=eqBase, sc=0;
  #pragma unroll
  for (int i=0;i<16;++i){
    unsigned x = v[i];
    if (x==T){ if (eq<extra) sc++; eq++; }
    else if (x>T) sc++;
  }
  unsigned inc2 = (unsigned)sc;
  #pragma unroll
  for (int off=1; off<64; off<<=1){
    unsigned o = __shfl_up(inc2, off);
    if (lane >= off) inc2 += o;
  }
  __syncthreads();                    // all reads of s_wsum done before rewrite
  if (lane==63) s_wsum[wid] = inc2;
  __syncthreads();
  unsigned wbase2 = 0;
  for (int w=0; w<wid; ++w) wbase2 += s_wsum[w];
  int pos = (int)(wbase2 + inc2) - sc;

  // ---- emit (ascending n within thread; global order = thread order)
  eq=eqBase;
  #pragma unroll
  for (int i=0;i<16;++i){
    unsigned x = v[i];
    int f=0;
    if (x==T){ if (eq<extra) f=1; eq++; }
    else if (x>T) f=1;
    if (f){
      int n = tid*16 + i;
      outIdxF[(size_t)b*KSEL + pos] = (float)n;
      selIdx[(size_t)b*KSEL + pos] = n;
      pos++;
    }
  }
}

// ---------------------------------------------------------------------------
// Gather selected rows. (unchanged — proven)
// ---------------------------------------------------------------------------
__global__ __launch_bounds__(256) void gather_kernel(
    const float* __restrict__ feat, const int* __restrict__ selIdx,
    float* __restrict__ outSel)
{
  const int tid = threadIdx.x;
  const int row = blockIdx.x*2 + (tid>>7);
  const int c4 = tid & 127;
  const int b = row / KSEL;
  const int idx = selIdx[row];
  const float4 v = *reinterpret_cast<const float4*>(feat + ((size_t)b*NP + idx)*DD + c4*4);
  *reinterpret_cast<float4*>(outSel + (size_t)row*DD + c4*4) = v;
}

// ---------------------------------------------------------------------------
// Per-(b,c) top-8/bottom-8, lax.top_k tie semantics. (unchanged — proven)
// ---------------------------------------------------------------------------
__global__ __launch_bounds__(256) void top16_kernel(
    const float* __restrict__ attn, int* __restrict__ top16)
{
  __shared__ unsigned long long wkT[4][8];
  __shared__ unsigned long long wkB[4][8];
  const int tid = threadIdx.x;
  const int bid = blockIdx.x;
  const int lane = tid & 63, wid = tid >> 6;
  const float* a = attn + (size_t)bid*NP;

  unsigned long long t8[8], b8[8];
  #pragma unroll
  for (int i=0;i<8;++i){ t8[i]=0ull; b8[i]=~0ull; }

  for (int j=0;j<16;++j){
    const int n4 = tid + 256*j;
    const float4 v = *reinterpret_cast<const float4*>(a + 4*n4);
    const float xs[4] = {v.x, v.y, v.z, v.w};
    #pragma unroll
    for (int q=0;q<4;++q){
      const int n = 4*n4 + q;
      const unsigned vb = __float_as_uint(xs[q]);
      unsigned long long kt = ((unsigned long long)vb<<32) | (unsigned)(NP-1-n);
      if (kt > t8[7]){
        t8[7]=kt;
        #pragma unroll
        for (int i=7;i>0;--i){ if (t8[i]>t8[i-1]){ unsigned long long t=t8[i-1]; t8[i-1]=t8[i]; t8[i]=t; } }
      }
      unsigned long long kb = ((unsigned long long)vb<<32) | (unsigned)n;
      if (kb < b8[7]){
        b8[7]=kb;
        #pragma unroll
        for (int i=7;i>0;--i){ if (b8[i]<b8[i-1]){ unsigned long long t=b8[i-1]; b8[i-1]=b8[i]; b8[i]=t; } }
      }
    }
  }

  #pragma unroll
  for (int pick=0; pick<8; ++pick){
    unsigned long long loc = t8[0];
    #pragma unroll
    for (int i=1;i<8;++i) loc = t8[i]>loc ? t8[i] : loc;
    #pragma unroll
    for (int off=1; off<64; off<<=1){ unsigned long long o=__shfl_xor(loc,off); loc=o>loc?o:loc; }
    if (lane==0) wkT[wid][pick]=loc;
    #pragma unroll
    for (int i=0;i<8;++i) if (t8[i]==loc) t8[i]=0ull;
  }
  #pragma unroll
  for (int pick=0; pick<8; ++pick){
    unsigned long long loc = b8[0];
    #pragma unroll
    for (int i=1;i<8;++i) loc = b8[i]<loc ? b8[i] : loc;
    #pragma unroll
    for (int off=1; off<64; off<<=1){ unsigned long long o=__shfl_xor(loc,off); loc=o<loc?o:loc; }
    if (lane==0) wkB[wid][pick]=loc;
    #pragma unroll
    for (int i=0;i<8;++i) if (b8[i]==loc) b8[i]=~0ull;
  }
  __syncthreads();

  if (wid==0){
    unsigned long long k = (lane<32) ? wkT[lane>>3][lane&7] : 0ull;
    #pragma unroll
    for (int pick=0; pick<8; ++pick){
      unsigned long long loc = k;
      #pragma unroll
      for (int off=1; off<64; off<<=1){ unsigned long long o=__shfl_xor(loc,off); loc=o>loc?o:loc; }
      if (k==loc) k=0ull;
      if (lane==0) top16[bid*16+pick] = NP-1-(int)(loc & 0xFFFFFFFFull);
    }
    unsigned long long kb = (lane<32) ? wkB[lane>>3][lane&7] : ~0ull;
    #pragma unroll
    for (int pick=0; pick<8; ++pick){
      unsigned long long loc = kb;
      #pragma unroll
      for (int off=1; off<64; off<<=1){ unsigned long long o=__shfl_xor(loc,off); loc=o<loc?o:loc; }
      if (kb==loc) kb=~0ull;
      if (lane==0) top16[bid*16+8+pick] = (int)(loc & 0xFFFFFFFFull);
    }
  }
}

// ---------------------------------------------------------------------------
// Instance MLP + CE partial, one block per (b,c,r). (unchanged — proven)
// ---------------------------------------------------------------------------
__global__ __launch_bounds__(256) void mlp_kernel(
    const float* __restrict__ feat, const float* __restrict__ W1,
    const float* __restrict__ b1, const float* __restrict__ W2,
    const float* __restrict__ b2, const int* __restrict__ top16,
    float* __restrict__ cews)
{
  __shared__ float fS[DD];
  __shared__ float r0[4], r1[4];
  const int tid = threadIdx.x;
  const int bid = blockIdx.x;
  const int r = bid & 15, c = (bid >> 4) & 1, b = bid >> 5;
  const int lane = tid & 63, wid = tid >> 6;
  const int gi = top16[(b*2+c)*16 + r];
  if (tid < 128){
    float4 v = *reinterpret_cast<const float4*>(feat + ((size_t)b*NP + gi)*DD + tid*4);
    *reinterpret_cast<float4*>(&fS[tid*4]) = v;
  }
  __syncthreads();
  const float* w1c = W1 + (size_t)c*DD*HH;
  float a0=0.f,a1=0.f,a2=0.f,a3=0.f;
  #pragma unroll 4
  for (int d=0; d<DD; d+=4){
    a0 += fS[d+0]*w1c[(size_t)(d+0)*HH + tid];
    a1 += fS[d+1]*w1c[(size_t)(d+1)*HH + tid];
    a2 += fS[d+2]*w1c[(size_t)(d+2)*HH + tid];
    a3 += fS[d+3]*w1c[(size_t)(d+3)*HH + tid];
  }
  float h = fmaxf((a0+a1)+(a2+a3) + b1[c*HH+tid], 0.f);
  float p0 = h*W2[(size_t)(c*HH+tid)*2 + 0];
  float p1 = h*W2[(size_t)(c*HH+tid)*2 + 1];
  #pragma unroll
  for (int off=1; off<64; off<<=1){ p0+=__shfl_xor(p0,off); p1+=__shfl_xor(p1,off); }
  if (lane==0){ r0[wid]=p0; r1[wid]=p1; }
  __syncthreads();
  if (tid==0){
    float l0 = (r0[0]+r0[1])+(r0[2]+r0[3]) + b2[c*2+0];
    float l1 = (r1[0]+r1[1])+(r1[2]+r1[3]) + b2[c*2+1];
    float mm = fmaxf(l0,l1);
    float lse = mm + logf(expf(l0-mm)+expf(l1-mm));
    float chosen = (r<8) ? l1 : l0;
    cews[bid] = lse - chosen;
  }
}

__global__ void loss_kernel(const float* __restrict__ cews, float* __restrict__ out_loss){
  if (threadIdx.x==0 && blockIdx.x==0){
    float s=0.f;
    for (int i=0;i<128;++i) s += cews[i];
    out_loss[0] = s / 128.0f;
  }
}

extern "C" void kernel_launch(void* const* d_in, const int* in_sizes, int n_in,
                              void* d_out, int out_size, void* d_ws, size_t ws_size,
                              hipStream_t stream) {
  const float* feat = (const float*)d_in[0];
  const float* Wa   = (const float*)d_in[1];
  const float* ba   = (const float*)d_in[2];
  const float* Wbr  = (const float*)d_in[3];
  const float* bbr  = (const float*)d_in[4];
  const float* W1   = (const float*)d_in[5];
  const float* b1   = (const float*)d_in[6];
  const float* W2   = (const float*)d_in[7];
  const float* b2   = (const float*)d_in[8];
  float* out = (float*)d_out;
  float* ws  = (float*)d_ws;

  float* a_logits = ws + WS_ALOGIT;
  float* attn     = ws + WS_ATTN;
  int*   selIdx   = (int*)(ws + WS_SELIDX);
  float* mz       = ws + WS_MZ;
  int*   bcnt     = (int*)(ws + WS_BCNT);
  int*   blist    = (int*)(ws + WS_BLIST);
  int*   top16    = (int*)(ws + WS_TOP16);
  float* cews     = ws + WS_CE;

  unsigned short* WaT = (unsigned short*)d_out;   // head of selected region;
                                                  // fully overwritten by gather

  hipLaunchKernelGGL(waconv_kernel, dim3(DD/32, HH/32), dim3(32,8), 0, stream,
                     Wa, WaT);
  hipLaunchKernelGGL(gemm_mfma_kernel, dim3(TOTP/128), dim3(512), 0, stream,
                     feat, WaT, ba, Wbr, bbr, a_logits);
  hipLaunchKernelGGL(smstat_kernel, dim3(NB*CC), dim3(1024), 0, stream,
                     a_logits, mz);
  hipLaunchKernelGGL(selTF_kernel, dim3(NB), dim3(1024), 0, stream,
                     a_logits, mz, attn, out + OFF_COMB, bcnt, blist);
  hipLaunchKernelGGL(recomp_kernel, dim3(NB*BCAP), dim3(256), 0, stream,
                     feat, Wa, ba, Wbr, bbr, mz, bcnt, blist, out + OFF_COMB);
  hipLaunchKernelGGL(select_kernel, dim3(NB), dim3(1024), 0, stream,
                     out + OFF_COMB, out + OFF_IDX, selIdx);
  hipLaunchKernelGGL(gather_kernel, dim3(NB*KSEL/2), dim3(256), 0, stream,
                     feat, selIdx, out);
  hipLaunchKernelGGL(top16_kernel, dim3(NB*CC), dim3(256), 0, stream,
                     attn, top16);
  hipLaunchKernelGGL(mlp_kernel, dim3(NB*CC*16), dim3(256), 0, stream,
                     feat, W1, b1, W2, b2, top16, cews);
  hipLaunchKernelGGL(loss_kernel, dim3(1), dim3(64), 0, stream,
                     cews, out + OFF_LOSS);
}